// Round 2
// baseline (11286.266 us; speedup 1.0000x reference)
//
#include <hip/hip_runtime.h>
#include <math.h>

#define B_    32
#define T_    256
#define HID_  512
#define EMB_  512
#define G4_   2048   // 4*HID
#define VOC_  10000
#define NBLK_ 256    // blocks in the persistent recurrence kernel

// ---------------------------------------------------------------------------
// fp32 GEMM: C[M,N] = A[M,K] @ W[K,N] + bias[N]
// BM=128 BN=64 BK=16, 256 threads, 8x4 micro-tile per thread.
// GATHER: A-rows come from embedding[tokens], row r = t*32+b, tok = tokens[b*T+t]
// PERM:   output row mapping r=(t*32+b) -> out_row = b*256+t  (for final [B*T,V])
// ---------------------------------------------------------------------------
template<bool GATHER, bool PERM>
__global__ __launch_bounds__(256, 2)
void gemm_k(const float* __restrict__ A, const float* __restrict__ W,
            const float* __restrict__ bias, float* __restrict__ C,
            int M, int N, int K,
            const int* __restrict__ tokens, const float* __restrict__ emb)
{
    __shared__ float lds_a[16][132];   // [k][m], stride 132 -> conflict-free reads
    __shared__ float lds_b[16][64];    // [k][n]
    __shared__ int   tokLds[128];

    const int tid = threadIdx.x;
    const int m0 = blockIdx.y * 128;
    const int n0 = blockIdx.x * 64;

    if constexpr (GATHER) {
        if (tid < 128) {
            int r = m0 + tid;                       // r = t*32 + b
            tokLds[tid] = tokens[(r & 31) * T_ + (r >> 5)];
        }
        __syncthreads();
    }

    const int lrow = tid & 127;          // A-loader row 0..127
    const int lk4  = (tid >> 7) * 4;     // 0 or 4; covers k = lk4..+3 and lk4+8..+11
    const float* aptr;
    if constexpr (GATHER) aptr = emb + (size_t)tokLds[lrow] * EMB_;
    else                  aptr = A   + (size_t)(m0 + lrow) * K;

    const int bk = tid >> 4;             // B-loader k 0..15
    const int bn = (tid & 15) * 4;       // B-loader col 0..60

    float4 pa0, pa1, pb;

    auto load_tiles = [&](int s) {
        const int k0 = s * 16;
        pa0 = *(const float4*)(aptr + k0 + lk4);
        pa1 = *(const float4*)(aptr + k0 + lk4 + 8);
        const int wc = n0 + bn;
        const float* wp = W + (size_t)(k0 + bk) * N + wc;
        if (wc + 3 < N) {
            pb = *(const float4*)wp;
        } else {
            pb.x = (wc + 0 < N) ? wp[0] : 0.f;
            pb.y = (wc + 1 < N) ? wp[1] : 0.f;
            pb.z = (wc + 2 < N) ? wp[2] : 0.f;
            pb.w = (wc + 3 < N) ? wp[3] : 0.f;
        }
    };

    float acc[8][4];
    #pragma unroll
    for (int i = 0; i < 8; ++i)
        #pragma unroll
        for (int j = 0; j < 4; ++j) acc[i][j] = 0.f;

    const int tm = tid >> 4, tn = tid & 15;
    const int nsteps = K / 16;
    load_tiles(0);

    for (int s = 0; s < nsteps; ++s) {
        __syncthreads();
        lds_a[lk4 + 0][lrow] = pa0.x;
        lds_a[lk4 + 1][lrow] = pa0.y;
        lds_a[lk4 + 2][lrow] = pa0.z;
        lds_a[lk4 + 3][lrow] = pa0.w;
        lds_a[lk4 + 8][lrow]  = pa1.x;
        lds_a[lk4 + 9][lrow]  = pa1.y;
        lds_a[lk4 + 10][lrow] = pa1.z;
        lds_a[lk4 + 11][lrow] = pa1.w;
        *(float4*)&lds_b[bk][bn] = pb;
        __syncthreads();
        if (s + 1 < nsteps) load_tiles(s + 1);

        #pragma unroll
        for (int kk = 0; kk < 16; ++kk) {
            const float4 a0  = *(const float4*)&lds_a[kk][tm * 8];
            const float4 a1  = *(const float4*)&lds_a[kk][tm * 8 + 4];
            const float4 b0v = *(const float4*)&lds_b[kk][tn * 4];
            const float av[8] = {a0.x, a0.y, a0.z, a0.w, a1.x, a1.y, a1.z, a1.w};
            const float bv[4] = {b0v.x, b0v.y, b0v.z, b0v.w};
            #pragma unroll
            for (int i = 0; i < 8; ++i)
                #pragma unroll
                for (int j = 0; j < 4; ++j)
                    acc[i][j] += av[i] * bv[j];
        }
    }

    #pragma unroll
    for (int i = 0; i < 8; ++i) {
        const int r = m0 + tm * 8 + i;
        const size_t orow = PERM ? (size_t)((r & 31) * T_ + (r >> 5)) : (size_t)r;
        const int c0 = n0 + tn * 4;
        if (c0 + 3 < N) {
            float4 o;
            o.x = acc[i][0] + bias[c0 + 0];
            o.y = acc[i][1] + bias[c0 + 1];
            o.z = acc[i][2] + bias[c0 + 2];
            o.w = acc[i][3] + bias[c0 + 3];
            *(float4*)(C + orow * (size_t)N + c0) = o;
        } else {
            #pragma unroll
            for (int j = 0; j < 4; ++j)
                if (c0 + j < N) C[orow * (size_t)N + c0 + j] = acc[i][j] + bias[c0 + j];
        }
    }
}

// ---------------------------------------------------------------------------
// LSTM recurrence (one layer), persistent kernel: 256 WGs x 256 thr.
// Grid-wide sync per timestep via software barrier (device-scope atomics):
//   8 sharded arrival counters (bar[shard*32], shard = blk&7, 32 blocks each),
//   last arriver of a shard bumps root (bar[256]); all blocks spin on root.
//   Counters are monotonic (zeroed by hipMemsetAsync before launch).
// WG (bg=blk>>6, cg=blk&63): owns b in [bg*8, +8), j in [cg*8, +8).
// U slice held in REGISTERS (t-invariant): thread (jj, bgg, kc) holds
// u[g][kk] = U[kc*32+kk][cg*8+jj + 512g], kk<32.
// Per step: h[8b][512] -> LDS, each thread partial-dots its 32-K chunk for
// 4 gates x 4 b, LDS reduce over 16 kc, 64 threads do gates + c/h update.
// G (precomputed x@W+b) added at reduce. h ping-pongs between 2 global bufs
// (hbuf buffer 0 is pre-zeroed by hipMemsetAsync = h at t=0).
// ---------------------------------------------------------------------------
__global__ __launch_bounds__(256, 1)
void lstm_rec_k(const float* __restrict__ G, const float* __restrict__ U,
                float* __restrict__ Hout, float* __restrict__ hbuf,
                unsigned* __restrict__ bar)
{
    __shared__ float hlds[16 * 292];     // idx = kc*292 + b*36 + kk
    __shared__ float part[16][8][33];    // [kc][jj][bgg*16 + g*4 + bb]

    const int tid = threadIdx.x;
    const int bg  = blockIdx.x >> 6;     // 0..3
    const int cgr = blockIdx.x & 63;     // 0..63
    const int j0  = cgr * 8;
    const int b0  = bg * 8;

    const int jj  = tid >> 5;            // 0..7
    const int bgg = (tid >> 4) & 1;      // 0..1
    const int kc  = tid & 15;            // 0..15
    const int k0  = kc * 32;

    // persistent U slice in registers (t-invariant)
    float u[4][32];
    #pragma unroll
    for (int g = 0; g < 4; ++g)
        #pragma unroll
        for (int kk = 0; kk < 32; ++kk)
            u[g][kk] = U[(size_t)(k0 + kk) * G4_ + j0 + jj + (g << 9)];

    // reducer role (tid < 64): local (b=rb, j=rj)
    const int rb = tid >> 3;
    const int rj = tid & 7;
    float c_reg = 0.f;

    for (int t = 0; t < T_; ++t) {
        const float* hcur = hbuf + (t & 1) * (B_ * HID_);
        float*       hnxt = hbuf + ((t + 1) & 1) * (B_ * HID_);

        // prefetch this step's gate-pre (from G, written by a prior kernel)
        float zi = 0.f, zf = 0.f, zg = 0.f, zo = 0.f;
        if (tid < 64) {
            const float* gp = G + ((size_t)t * B_ + b0 + rb) * G4_ + j0 + rj;
            zi = gp[0]; zf = gp[512]; zg = gp[1024]; zo = gp[1536];
        }

        __syncthreads();   // hlds/part free from previous iteration
        // stage h[8][512] -> LDS (1024 float4s, 4/thread, coalesced)
        #pragma unroll
        for (int q = 0; q < 4; ++q) {
            int idx  = q * 256 + tid;
            int kcL  = idx >> 6;
            int bL   = (idx >> 3) & 7;
            int kk4  = (idx & 7) * 4;
            float4 v = *(const float4*)(hcur + (b0 + bL) * HID_ + kcL * 32 + kk4);
            *(float4*)&hlds[kcL * 292 + bL * 36 + kk4] = v;
        }
        __syncthreads();

        float acc[4][4];
        #pragma unroll
        for (int g = 0; g < 4; ++g)
            #pragma unroll
            for (int bb = 0; bb < 4; ++bb) acc[g][bb] = 0.f;

        #pragma unroll
        for (int kk4 = 0; kk4 < 8; ++kk4) {
            float4 hv0 = *(const float4*)&hlds[kc * 292 + (bgg * 4 + 0) * 36 + kk4 * 4];
            float4 hv1 = *(const float4*)&hlds[kc * 292 + (bgg * 4 + 1) * 36 + kk4 * 4];
            float4 hv2 = *(const float4*)&hlds[kc * 292 + (bgg * 4 + 2) * 36 + kk4 * 4];
            float4 hv3 = *(const float4*)&hlds[kc * 292 + (bgg * 4 + 3) * 36 + kk4 * 4];
            const float hb[4][4] = {{hv0.x, hv0.y, hv0.z, hv0.w},
                                    {hv1.x, hv1.y, hv1.z, hv1.w},
                                    {hv2.x, hv2.y, hv2.z, hv2.w},
                                    {hv3.x, hv3.y, hv3.z, hv3.w}};
            #pragma unroll
            for (int w = 0; w < 4; ++w) {
                const int kk = kk4 * 4 + w;
                #pragma unroll
                for (int g = 0; g < 4; ++g) {
                    acc[g][0] += u[g][kk] * hb[0][w];
                    acc[g][1] += u[g][kk] * hb[1][w];
                    acc[g][2] += u[g][kk] * hb[2][w];
                    acc[g][3] += u[g][kk] * hb[3][w];
                }
            }
        }

        #pragma unroll
        for (int g = 0; g < 4; ++g)
            #pragma unroll
            for (int bb = 0; bb < 4; ++bb)
                part[kc][jj][bgg * 16 + g * 4 + bb] = acc[g][bb];
        __syncthreads();

        if (tid < 64) {
            const int bggr = rb >> 2, bbr = rb & 3;
            float si = 0.f, sf = 0.f, sg = 0.f, so = 0.f;
            #pragma unroll
            for (int k = 0; k < 16; ++k) {
                si += part[k][rj][bggr * 16 + 0 + bbr];
                sf += part[k][rj][bggr * 16 + 4 + bbr];
                sg += part[k][rj][bggr * 16 + 8 + bbr];
                so += part[k][rj][bggr * 16 + 12 + bbr];
            }
            zi += si; zf += sf; zg += sg; zo += so;
            const float i_ = 1.f / (1.f + expf(-zi));
            const float f_ = 1.f / (1.f + expf(-zf));
            const float g_ = tanhf(zg);
            const float o_ = 1.f / (1.f + expf(-zo));
            c_reg = f_ * c_reg + i_ * g_;
            const float h_ = o_ * tanhf(c_reg);
            hnxt[(b0 + rb) * HID_ + j0 + rj] = h_;
            Hout[(size_t)t * (B_ * HID_) + (b0 + rb) * HID_ + j0 + rj] = h_;
        }

        // ---- software grid barrier (skip after last step) ----
        if (t + 1 < T_) {
            __syncthreads();   // all waves' global stores drained (vmcnt) before arrival
            if (tid == 0) {
                const unsigned shard = (unsigned)(blockIdx.x & 7) * 32u;
                unsigned old = __hip_atomic_fetch_add(&bar[shard], 1u,
                                   __ATOMIC_ACQ_REL, __HIP_MEMORY_SCOPE_AGENT);
                if (old + 1u == (unsigned)(t + 1) * (NBLK_ / 8)) {
                    __hip_atomic_fetch_add(&bar[256], 1u,
                                   __ATOMIC_ACQ_REL, __HIP_MEMORY_SCOPE_AGENT);
                }
                const unsigned target = (unsigned)(t + 1) * 8u;
                unsigned guard = 0;
                while (__hip_atomic_load(&bar[256],
                           __ATOMIC_ACQUIRE, __HIP_MEMORY_SCOPE_AGENT) < target) {
                    __builtin_amdgcn_s_sleep(4);
                    if (++guard > 50000000u) break;   // bail instead of hanging harness
                }
            }
            __syncthreads();
        }
    }
}

// ---------------------------------------------------------------------------
extern "C" void kernel_launch(void* const* d_in, const int* in_sizes, int n_in,
                              void* d_out, int out_size, void* d_ws, size_t ws_size,
                              hipStream_t stream)
{
    const int*   tokens = (const int*)  d_in[0];
    const float* emb    = (const float*)d_in[1];
    const float* W0     = (const float*)d_in[2];
    const float* U0     = (const float*)d_in[3];
    const float* b0     = (const float*)d_in[4];
    const float* W1     = (const float*)d_in[5];
    const float* U1     = (const float*)d_in[6];
    const float* b1     = (const float*)d_in[7];
    const float* Wout   = (const float*)d_in[8];
    const float* bout   = (const float*)d_in[9];
    float* out = (float*)d_out;

    // G (gate pre-activations, 8192x2048 fp32 = 64 MiB) lives in d_out's
    // scratch space (312 MiB total); it is dead before the final GEMM
    // overwrites all of d_out. d_ws only needs ~16.2 MiB:
    float* ws   = (float*)d_ws;
    float*    H    = ws;                                   // 8192*512 fp32 (16 MiB)
    float*    hbuf = H + (size_t)8192 * 512;               // 2*32*512 ping-pong h
    unsigned* bar  = (unsigned*)(hbuf + 2 * B_ * HID_);    // 1024 u32 barrier state
    float*    G    = out;                                  // 8192*2048 in d_out

    dim3 blk(256);

    // G = gather(emb,tokens) @ W0 + b0        [T*B, 2048]
    gemm_k<true, false><<<dim3(G4_ / 64, 8192 / 128), blk, 0, stream>>>(
        nullptr, W0, b0, G, 8192, G4_, 512, tokens, emb);

    // layer-0 recurrence -> H ([T,B,512])
    hipMemsetAsync(hbuf, 0, B_ * HID_ * sizeof(float), stream);  // h[0] = 0
    hipMemsetAsync(bar, 0, 1024 * sizeof(unsigned), stream);     // barrier = 0
    lstm_rec_k<<<dim3(NBLK_), blk, 0, stream>>>(G, U0, H, hbuf, bar);

    // G = H @ W1 + b1
    gemm_k<false, false><<<dim3(G4_ / 64, 8192 / 128), blk, 0, stream>>>(
        H, W1, b1, G, 8192, G4_, 512, nullptr, nullptr);

    // layer-1 recurrence -> H
    hipMemsetAsync(hbuf, 0, B_ * HID_ * sizeof(float), stream);
    hipMemsetAsync(bar, 0, 1024 * sizeof(unsigned), stream);
    lstm_rec_k<<<dim3(NBLK_), blk, 0, stream>>>(G, U1, H, hbuf, bar);

    // out[b*T+t, :] = H[t*B+b, :] @ W_out + b_out
    gemm_k<false, true><<<dim3((VOC_ + 63) / 64, 8192 / 128), blk, 0, stream>>>(
        H, Wout, bout, out, 8192, VOC_, 512, nullptr, nullptr);
}

// Round 3
// 3997.076 us; speedup vs baseline: 2.8236x; 2.8236x over previous
//
#include <hip/hip_runtime.h>
#include <math.h>

#define B_    32
#define T_    256
#define HID_  512
#define EMB_  512
#define G4_   2048   // 4*HID
#define VOC_  10000
#define NBLK_ 256    // blocks in the persistent recurrence kernel

typedef float f32x4 __attribute__((ext_vector_type(4)));

// Coherent (cross-XCD) access helpers: sc0 sc1 = bypass L1/L2, talk to the
// Infinity-Cache coherence point directly. No buffer_inv / wbl2 anywhere.
__device__ __forceinline__ void load4_coherent(const float* p0, const float* p1,
                                               const float* p2, const float* p3,
                                               f32x4& a, f32x4& b, f32x4& c, f32x4& d)
{
    asm volatile(
        "global_load_dwordx4 %0, %4, off sc0 sc1\n\t"
        "global_load_dwordx4 %1, %5, off sc0 sc1\n\t"
        "global_load_dwordx4 %2, %6, off sc0 sc1\n\t"
        "global_load_dwordx4 %3, %7, off sc0 sc1\n\t"
        "s_waitcnt vmcnt(0)"
        : "=&v"(a), "=&v"(b), "=&v"(c), "=&v"(d)
        : "v"(p0), "v"(p1), "v"(p2), "v"(p3)
        : "memory");
}

__device__ __forceinline__ void store_coherent(float* p, float x)
{
    asm volatile("global_store_dword %0, %1, off sc0 sc1"
                 :: "v"(p), "v"(x) : "memory");
}

// ---------------------------------------------------------------------------
// fp32 GEMM: C[M,N] = A[M,K] @ W[K,N] + bias[N]
// BM=128 BN=64 BK=16, 256 threads, 8x4 micro-tile per thread.
// GATHER: A-rows come from embedding[tokens], row r = t*32+b, tok = tokens[b*T+t]
// PERM:   output row mapping r=(t*32+b) -> out_row = b*256+t  (for final [B*T,V])
// ---------------------------------------------------------------------------
template<bool GATHER, bool PERM>
__global__ __launch_bounds__(256, 2)
void gemm_k(const float* __restrict__ A, const float* __restrict__ W,
            const float* __restrict__ bias, float* __restrict__ C,
            int M, int N, int K,
            const int* __restrict__ tokens, const float* __restrict__ emb)
{
    __shared__ float lds_a[16][132];   // [k][m], stride 132 -> conflict-free reads
    __shared__ float lds_b[16][64];    // [k][n]
    __shared__ int   tokLds[128];

    const int tid = threadIdx.x;
    const int m0 = blockIdx.y * 128;
    const int n0 = blockIdx.x * 64;

    if constexpr (GATHER) {
        if (tid < 128) {
            int r = m0 + tid;                       // r = t*32 + b
            tokLds[tid] = tokens[(r & 31) * T_ + (r >> 5)];
        }
        __syncthreads();
    }

    const int lrow = tid & 127;          // A-loader row 0..127
    const int lk4  = (tid >> 7) * 4;     // 0 or 4; covers k = lk4..+3 and lk4+8..+11
    const float* aptr;
    if constexpr (GATHER) aptr = emb + (size_t)tokLds[lrow] * EMB_;
    else                  aptr = A   + (size_t)(m0 + lrow) * K;

    const int bk = tid >> 4;             // B-loader k 0..15
    const int bn = (tid & 15) * 4;       // B-loader col 0..60

    float4 pa0, pa1, pb;

    auto load_tiles = [&](int s) {
        const int k0 = s * 16;
        pa0 = *(const float4*)(aptr + k0 + lk4);
        pa1 = *(const float4*)(aptr + k0 + lk4 + 8);
        const int wc = n0 + bn;
        const float* wp = W + (size_t)(k0 + bk) * N + wc;
        if (wc + 3 < N) {
            pb = *(const float4*)wp;
        } else {
            pb.x = (wc + 0 < N) ? wp[0] : 0.f;
            pb.y = (wc + 1 < N) ? wp[1] : 0.f;
            pb.z = (wc + 2 < N) ? wp[2] : 0.f;
            pb.w = (wc + 3 < N) ? wp[3] : 0.f;
        }
    };

    float acc[8][4];
    #pragma unroll
    for (int i = 0; i < 8; ++i)
        #pragma unroll
        for (int j = 0; j < 4; ++j) acc[i][j] = 0.f;

    const int tm = tid >> 4, tn = tid & 15;
    const int nsteps = K / 16;
    load_tiles(0);

    for (int s = 0; s < nsteps; ++s) {
        __syncthreads();
        lds_a[lk4 + 0][lrow] = pa0.x;
        lds_a[lk4 + 1][lrow] = pa0.y;
        lds_a[lk4 + 2][lrow] = pa0.z;
        lds_a[lk4 + 3][lrow] = pa0.w;
        lds_a[lk4 + 8][lrow]  = pa1.x;
        lds_a[lk4 + 9][lrow]  = pa1.y;
        lds_a[lk4 + 10][lrow] = pa1.z;
        lds_a[lk4 + 11][lrow] = pa1.w;
        *(float4*)&lds_b[bk][bn] = pb;
        __syncthreads();
        if (s + 1 < nsteps) load_tiles(s + 1);

        #pragma unroll
        for (int kk = 0; kk < 16; ++kk) {
            const float4 a0  = *(const float4*)&lds_a[kk][tm * 8];
            const float4 a1  = *(const float4*)&lds_a[kk][tm * 8 + 4];
            const float4 b0v = *(const float4*)&lds_b[kk][tn * 4];
            const float av[8] = {a0.x, a0.y, a0.z, a0.w, a1.x, a1.y, a1.z, a1.w};
            const float bv[4] = {b0v.x, b0v.y, b0v.z, b0v.w};
            #pragma unroll
            for (int i = 0; i < 8; ++i)
                #pragma unroll
                for (int j = 0; j < 4; ++j)
                    acc[i][j] += av[i] * bv[j];
        }
    }

    #pragma unroll
    for (int i = 0; i < 8; ++i) {
        const int r = m0 + tm * 8 + i;
        const size_t orow = PERM ? (size_t)((r & 31) * T_ + (r >> 5)) : (size_t)r;
        const int c0 = n0 + tn * 4;
        if (c0 + 3 < N) {
            float4 o;
            o.x = acc[i][0] + bias[c0 + 0];
            o.y = acc[i][1] + bias[c0 + 1];
            o.z = acc[i][2] + bias[c0 + 2];
            o.w = acc[i][3] + bias[c0 + 3];
            *(float4*)(C + orow * (size_t)N + c0) = o;
        } else {
            #pragma unroll
            for (int j = 0; j < 4; ++j)
                if (c0 + j < N) C[orow * (size_t)N + c0 + j] = acc[i][j] + bias[c0 + j];
        }
    }
}

// ---------------------------------------------------------------------------
// LSTM recurrence (one layer), persistent kernel: 256 WGs x 256 thr.
// Per-timestep sync is per-BATCH-GROUP (4 independent groups of 64 blocks):
// block (bg,cg) only consumes h rows [bg*8, bg*8+8) which are produced by the
// 64 blocks sharing bg. Sync = RELAXED agent atomics on bar[bg*64] (no
// acquire/release -> no buffer_inv/wbl2 L2 nukes). h goes through IF$ via
// sc0|sc1 stores/loads (true coherence point), everything else stays cached.
// WG (bg=blk>>6, cg=blk&63): owns b in [bg*8, +8), j in [cg*8, +8).
// U slice held in REGISTERS (t-invariant).
// ---------------------------------------------------------------------------
__global__ __launch_bounds__(256, 1)
void lstm_rec_k(const float* __restrict__ G, const float* __restrict__ U,
                float* __restrict__ Hout, float* __restrict__ hbuf,
                unsigned* __restrict__ bar)
{
    __shared__ float hlds[16 * 292];     // idx = kc*292 + b*36 + kk
    __shared__ float part[16][8][33];    // [kc][jj][bgg*16 + g*4 + bb]

    const int tid = threadIdx.x;
    const int bg  = blockIdx.x >> 6;     // 0..3
    const int cgr = blockIdx.x & 63;     // 0..63
    const int j0  = cgr * 8;
    const int b0  = bg * 8;

    const int jj  = tid >> 5;            // 0..7
    const int bgg = (tid >> 4) & 1;      // 0..1
    const int kc  = tid & 15;            // 0..15
    const int k0  = kc * 32;

    // persistent U slice in registers (t-invariant)
    float u[4][32];
    #pragma unroll
    for (int g = 0; g < 4; ++g)
        #pragma unroll
        for (int kk = 0; kk < 32; ++kk)
            u[g][kk] = U[(size_t)(k0 + kk) * G4_ + j0 + jj + (g << 9)];

    // reducer role (tid < 64): local (b=rb, j=rj)
    const int rb = tid >> 3;
    const int rj = tid & 7;
    float c_reg = 0.f;

    unsigned* grp_bar = bar + bg * 64;   // 256B apart per group

    for (int t = 0; t < T_; ++t) {
        const float* hcur = hbuf + (t & 1) * (B_ * HID_);
        float*       hnxt = hbuf + ((t + 1) & 1) * (B_ * HID_);

        // prefetch this step's gate-pre (cached loads; G is read-once)
        float zi = 0.f, zf = 0.f, zg = 0.f, zo = 0.f;
        if (tid < 64) {
            const float* gp = G + ((size_t)t * B_ + b0 + rb) * G4_ + j0 + rj;
            zi = gp[0]; zf = gp[512]; zg = gp[1024]; zo = gp[1536];
        }

        __syncthreads();   // hlds/part free from previous iteration
        // stage h[8][512] -> LDS: 4 coherent float4 loads/thread (bypass L1/L2)
        {
            const float* p[4];
            int kcL[4], bL[4], kk4[4];
            #pragma unroll
            for (int q = 0; q < 4; ++q) {
                int idx = q * 256 + tid;
                kcL[q] = idx >> 6;
                bL[q]  = (idx >> 3) & 7;
                kk4[q] = (idx & 7) * 4;
                p[q] = hcur + (b0 + bL[q]) * HID_ + kcL[q] * 32 + kk4[q];
            }
            f32x4 v0, v1, v2, v3;
            load4_coherent(p[0], p[1], p[2], p[3], v0, v1, v2, v3);
            *(f32x4*)&hlds[kcL[0] * 292 + bL[0] * 36 + kk4[0]] = v0;
            *(f32x4*)&hlds[kcL[1] * 292 + bL[1] * 36 + kk4[1]] = v1;
            *(f32x4*)&hlds[kcL[2] * 292 + bL[2] * 36 + kk4[2]] = v2;
            *(f32x4*)&hlds[kcL[3] * 292 + bL[3] * 36 + kk4[3]] = v3;
        }
        __syncthreads();

        float acc[4][4];
        #pragma unroll
        for (int g = 0; g < 4; ++g)
            #pragma unroll
            for (int bb = 0; bb < 4; ++bb) acc[g][bb] = 0.f;

        #pragma unroll
        for (int kk4 = 0; kk4 < 8; ++kk4) {
            float4 hv0 = *(const float4*)&hlds[kc * 292 + (bgg * 4 + 0) * 36 + kk4 * 4];
            float4 hv1 = *(const float4*)&hlds[kc * 292 + (bgg * 4 + 1) * 36 + kk4 * 4];
            float4 hv2 = *(const float4*)&hlds[kc * 292 + (bgg * 4 + 2) * 36 + kk4 * 4];
            float4 hv3 = *(const float4*)&hlds[kc * 292 + (bgg * 4 + 3) * 36 + kk4 * 4];
            const float hb[4][4] = {{hv0.x, hv0.y, hv0.z, hv0.w},
                                    {hv1.x, hv1.y, hv1.z, hv1.w},
                                    {hv2.x, hv2.y, hv2.z, hv2.w},
                                    {hv3.x, hv3.y, hv3.z, hv3.w}};
            #pragma unroll
            for (int w = 0; w < 4; ++w) {
                const int kk = kk4 * 4 + w;
                #pragma unroll
                for (int g = 0; g < 4; ++g) {
                    acc[g][0] += u[g][kk] * hb[0][w];
                    acc[g][1] += u[g][kk] * hb[1][w];
                    acc[g][2] += u[g][kk] * hb[2][w];
                    acc[g][3] += u[g][kk] * hb[3][w];
                }
            }
        }

        #pragma unroll
        for (int g = 0; g < 4; ++g)
            #pragma unroll
            for (int bb = 0; bb < 4; ++bb)
                part[kc][jj][bgg * 16 + g * 4 + bb] = acc[g][bb];
        __syncthreads();

        if (tid < 64) {
            const int bggr = rb >> 2, bbr = rb & 3;
            float si = 0.f, sf = 0.f, sg = 0.f, so = 0.f;
            #pragma unroll
            for (int k = 0; k < 16; ++k) {
                si += part[k][rj][bggr * 16 + 0 + bbr];
                sf += part[k][rj][bggr * 16 + 4 + bbr];
                sg += part[k][rj][bggr * 16 + 8 + bbr];
                so += part[k][rj][bggr * 16 + 12 + bbr];
            }
            zi += si; zf += sf; zg += sg; zo += so;
            const float i_ = 1.f / (1.f + expf(-zi));
            const float f_ = 1.f / (1.f + expf(-zf));
            const float g_ = tanhf(zg);
            const float o_ = 1.f / (1.f + expf(-zo));
            c_reg = f_ * c_reg + i_ * g_;
            const float h_ = o_ * tanhf(c_reg);
            store_coherent(&hnxt[(b0 + rb) * HID_ + j0 + rj], h_);   // -> IF$
            Hout[(size_t)t * (B_ * HID_) + (b0 + rb) * HID_ + j0 + rj] = h_;  // cached
        }

        // ---- per-group software barrier (64 blocks), RELAXED atomics only ----
        if (t + 1 < T_) {
            __syncthreads();   // drains vmcnt: coherent h stores are at IF$ now
            if (tid == 0) {
                __hip_atomic_fetch_add(grp_bar, 1u,
                                       __ATOMIC_RELAXED, __HIP_MEMORY_SCOPE_AGENT);
                const unsigned target = (unsigned)(t + 1) * 64u;
                unsigned guard = 0;
                while (__hip_atomic_load(grp_bar,
                           __ATOMIC_RELAXED, __HIP_MEMORY_SCOPE_AGENT) < target) {
                    __builtin_amdgcn_s_sleep(1);
                    if (++guard > 50000000u) break;   // hang-safety
                }
            }
            __syncthreads();
        }
    }
}

// ---------------------------------------------------------------------------
extern "C" void kernel_launch(void* const* d_in, const int* in_sizes, int n_in,
                              void* d_out, int out_size, void* d_ws, size_t ws_size,
                              hipStream_t stream)
{
    const int*   tokens = (const int*)  d_in[0];
    const float* emb    = (const float*)d_in[1];
    const float* W0     = (const float*)d_in[2];
    const float* U0     = (const float*)d_in[3];
    const float* b0     = (const float*)d_in[4];
    const float* W1     = (const float*)d_in[5];
    const float* U1     = (const float*)d_in[6];
    const float* b1     = (const float*)d_in[7];
    const float* Wout   = (const float*)d_in[8];
    const float* bout   = (const float*)d_in[9];
    float* out = (float*)d_out;

    // G (8192x2048 fp32 = 64 MiB) lives in d_out (312 MiB); dead before the
    // final GEMM overwrites all of d_out. d_ws needs ~16.2 MiB:
    float* ws   = (float*)d_ws;
    float*    H    = ws;                                   // 8192*512 fp32 (16 MiB)
    float*    hbuf = H + (size_t)8192 * 512;               // 2*32*512 ping-pong h
    unsigned* bar  = (unsigned*)(hbuf + 2 * B_ * HID_);    // 1024 u32 barrier state
    float*    G    = out;                                  // 8192*2048 in d_out

    dim3 blk(256);

    // G = gather(emb,tokens) @ W0 + b0        [T*B, 2048]
    gemm_k<true, false><<<dim3(G4_ / 64, 8192 / 128), blk, 0, stream>>>(
        nullptr, W0, b0, G, 8192, G4_, 512, tokens, emb);

    // layer-0 recurrence -> H ([T,B,512])
    hipMemsetAsync(hbuf, 0, B_ * HID_ * sizeof(float), stream);  // h[0] = 0
    hipMemsetAsync(bar, 0, 1024 * sizeof(unsigned), stream);     // barrier = 0
    lstm_rec_k<<<dim3(NBLK_), blk, 0, stream>>>(G, U0, H, hbuf, bar);

    // G = H @ W1 + b1
    gemm_k<false, false><<<dim3(G4_ / 64, 8192 / 128), blk, 0, stream>>>(
        H, W1, b1, G, 8192, G4_, 512, nullptr, nullptr);

    // layer-1 recurrence -> H
    hipMemsetAsync(hbuf, 0, B_ * HID_ * sizeof(float), stream);
    hipMemsetAsync(bar, 0, 1024 * sizeof(unsigned), stream);
    lstm_rec_k<<<dim3(NBLK_), blk, 0, stream>>>(G, U1, H, hbuf, bar);

    // out[b*T+t, :] = H[t*B+b, :] @ W_out + b_out
    gemm_k<false, true><<<dim3((VOC_ + 63) / 64, 8192 / 128), blk, 0, stream>>>(
        H, Wout, bout, out, 8192, VOC_, 512, nullptr, nullptr);
}

// Round 4
// 3435.090 us; speedup vs baseline: 3.2856x; 1.1636x over previous
//
#include <hip/hip_runtime.h>
#include <math.h>

#define B_    32
#define T_    256
#define HID_  512
#define EMB_  512
#define G4_   2048   // 4*HID
#define VOC_  10000
#define NBLK_ 256    // blocks in the persistent recurrence kernel

typedef float f32x4 __attribute__((ext_vector_type(4)));

// Coherent (cross-XCD) access helpers: sc0 sc1 = bypass L1/L2, talk to the
// Infinity-Cache coherence point directly. No buffer_inv / wbl2 anywhere.
__device__ __forceinline__ void load4_coherent(const float* p0, const float* p1,
                                               const float* p2, const float* p3,
                                               f32x4& a, f32x4& b, f32x4& c, f32x4& d)
{
    asm volatile(
        "global_load_dwordx4 %0, %4, off sc0 sc1\n\t"
        "global_load_dwordx4 %1, %5, off sc0 sc1\n\t"
        "global_load_dwordx4 %2, %6, off sc0 sc1\n\t"
        "global_load_dwordx4 %3, %7, off sc0 sc1\n\t"
        "s_waitcnt vmcnt(0)"
        : "=&v"(a), "=&v"(b), "=&v"(c), "=&v"(d)
        : "v"(p0), "v"(p1), "v"(p2), "v"(p3)
        : "memory");
}

__device__ __forceinline__ void store_coherent(float* p, float x)
{
    asm volatile("global_store_dword %0, %1, off sc0 sc1"
                 :: "v"(p), "v"(x) : "memory");
}

__device__ __forceinline__ float fsigm(float x)
{
    float e = exp2f(x * -1.4426950408889634f);
    return __builtin_amdgcn_rcpf(1.f + e);
}
__device__ __forceinline__ float ftanh(float x)
{
    float e = exp2f(x * 2.8853900817779268f);
    return 1.f - 2.f * __builtin_amdgcn_rcpf(e + 1.f);
}

// ---------------------------------------------------------------------------
// fp32 GEMM: C[M,N] = A[M,K] @ W[K,N] + bias[N]
// BM=128 BN=64 BK=16, 256 threads, 8x4 micro-tile per thread.
// GATHER: A-rows come from embedding[tokens], row r = t*32+b, tok = tokens[b*T+t]
// PERM:   output row mapping r=(t*32+b) -> out_row = b*256+t  (for final [B*T,V])
// STOREG: store C in the recurrence-swizzled G layout:
//         addr = ((t*4+bgrp)*64 + jblk)*256 + bb*32 + g*8 + jj
//         (t=r>>5, bgrp=(r>>3)&3, bb=r&7, g=c>>9, jblk=(c&511)>>3, jj=c&7)
// ---------------------------------------------------------------------------
template<bool GATHER, bool PERM, bool STOREG>
__global__ __launch_bounds__(256, 2)
void gemm_k(const float* __restrict__ A, const float* __restrict__ W,
            const float* __restrict__ bias, float* __restrict__ C,
            int M, int N, int K,
            const int* __restrict__ tokens, const float* __restrict__ emb)
{
    __shared__ float lds_a[16][132];   // [k][m], stride 132 -> conflict-free reads
    __shared__ float lds_b[16][64];    // [k][n]
    __shared__ int   tokLds[128];

    const int tid = threadIdx.x;
    const int m0 = blockIdx.y * 128;
    const int n0 = blockIdx.x * 64;

    if constexpr (GATHER) {
        if (tid < 128) {
            int r = m0 + tid;                       // r = t*32 + b
            tokLds[tid] = tokens[(r & 31) * T_ + (r >> 5)];
        }
        __syncthreads();
    }

    const int lrow = tid & 127;          // A-loader row 0..127
    const int lk4  = (tid >> 7) * 4;     // 0 or 4; covers k = lk4..+3 and lk4+8..+11
    const float* aptr;
    if constexpr (GATHER) aptr = emb + (size_t)tokLds[lrow] * EMB_;
    else                  aptr = A   + (size_t)(m0 + lrow) * K;

    const int bk = tid >> 4;             // B-loader k 0..15
    const int bn = (tid & 15) * 4;       // B-loader col 0..60

    float4 pa0, pa1, pb;

    auto load_tiles = [&](int s) {
        const int k0 = s * 16;
        pa0 = *(const float4*)(aptr + k0 + lk4);
        pa1 = *(const float4*)(aptr + k0 + lk4 + 8);
        const int wc = n0 + bn;
        const float* wp = W + (size_t)(k0 + bk) * N + wc;
        if (wc + 3 < N) {
            pb = *(const float4*)wp;
        } else {
            pb.x = (wc + 0 < N) ? wp[0] : 0.f;
            pb.y = (wc + 1 < N) ? wp[1] : 0.f;
            pb.z = (wc + 2 < N) ? wp[2] : 0.f;
            pb.w = (wc + 3 < N) ? wp[3] : 0.f;
        }
    };

    float acc[8][4];
    #pragma unroll
    for (int i = 0; i < 8; ++i)
        #pragma unroll
        for (int j = 0; j < 4; ++j) acc[i][j] = 0.f;

    const int tm = tid >> 4, tn = tid & 15;
    const int nsteps = K / 16;
    load_tiles(0);

    for (int s = 0; s < nsteps; ++s) {
        __syncthreads();
        lds_a[lk4 + 0][lrow] = pa0.x;
        lds_a[lk4 + 1][lrow] = pa0.y;
        lds_a[lk4 + 2][lrow] = pa0.z;
        lds_a[lk4 + 3][lrow] = pa0.w;
        lds_a[lk4 + 8][lrow]  = pa1.x;
        lds_a[lk4 + 9][lrow]  = pa1.y;
        lds_a[lk4 + 10][lrow] = pa1.z;
        lds_a[lk4 + 11][lrow] = pa1.w;
        *(float4*)&lds_b[bk][bn] = pb;
        __syncthreads();
        if (s + 1 < nsteps) load_tiles(s + 1);

        #pragma unroll
        for (int kk = 0; kk < 16; ++kk) {
            const float4 a0  = *(const float4*)&lds_a[kk][tm * 8];
            const float4 a1  = *(const float4*)&lds_a[kk][tm * 8 + 4];
            const float4 b0v = *(const float4*)&lds_b[kk][tn * 4];
            const float av[8] = {a0.x, a0.y, a0.z, a0.w, a1.x, a1.y, a1.z, a1.w};
            const float bv[4] = {b0v.x, b0v.y, b0v.z, b0v.w};
            #pragma unroll
            for (int i = 0; i < 8; ++i)
                #pragma unroll
                for (int j = 0; j < 4; ++j)
                    acc[i][j] += av[i] * bv[j];
        }
    }

    #pragma unroll
    for (int i = 0; i < 8; ++i) {
        const int r = m0 + tm * 8 + i;
        const int c0 = n0 + tn * 4;
        if constexpr (STOREG) {
            const int t    = r >> 5;
            const int bgrp = (r >> 3) & 3;
            const int bb   = r & 7;
            const int g    = c0 >> 9;
            const int jf   = c0 & 511;
            const int jblk = jf >> 3;
            const int jjs  = jf & 7;
            float4 o;
            o.x = acc[i][0] + bias[c0 + 0];
            o.y = acc[i][1] + bias[c0 + 1];
            o.z = acc[i][2] + bias[c0 + 2];
            o.w = acc[i][3] + bias[c0 + 3];
            const size_t addr = (((size_t)t * 4 + bgrp) * 64 + jblk) * 256
                                + bb * 32 + g * 8 + jjs;
            *(float4*)(C + addr) = o;
        } else {
            const size_t orow = PERM ? (size_t)((r & 31) * T_ + (r >> 5)) : (size_t)r;
            if (c0 + 3 < N) {
                float4 o;
                o.x = acc[i][0] + bias[c0 + 0];
                o.y = acc[i][1] + bias[c0 + 1];
                o.z = acc[i][2] + bias[c0 + 2];
                o.w = acc[i][3] + bias[c0 + 3];
                *(float4*)(C + orow * (size_t)N + c0) = o;
            } else {
                #pragma unroll
                for (int j = 0; j < 4; ++j)
                    if (c0 + j < N) C[orow * (size_t)N + c0 + j] = acc[i][j] + bias[c0 + j];
            }
        }
    }
}

// ---------------------------------------------------------------------------
// LSTM recurrence, persistent kernel: 256 WGs x 256 thr, per-batch-group sync
// (4 independent groups of 64 blocks; RELAXED agent atomics; h via IF$).
// Thread (jj = tid>>5, kc = tid&31): owns K-chunk [kc*16, +16) for ALL
// 4 gates x 8 batches at column j0+jj. u[4][16] in registers (t-invariant).
// Per step: h[8][512] -> LDS (stride-20 padded, b128-aligned, bank-balanced),
// 512 FMA/thread, then 5-stage __shfl_xor reduce-scatter over the 32 kc lanes
// (lane kc ends with z for gate kc>>3, batch kc&7), 3-shuffle gate exchange,
// gate math on all lanes, g==0 lanes own c and store h.
// G is read pre-swizzled (1 coalesced float/thread), prefetched 1 step ahead.
// ---------------------------------------------------------------------------
__global__ __launch_bounds__(256, 1)
void lstm_rec_k(const float* __restrict__ G, const float* __restrict__ U,
                float* __restrict__ Hout, float* __restrict__ hbuf,
                unsigned* __restrict__ bar)
{
    __shared__ float hlds[8 * 640];      // [b][chunk kc: 16 floats + 4 pad]

    const int tid = threadIdx.x;
    const int bg  = blockIdx.x >> 6;     // 0..3  batch group
    const int cgr = blockIdx.x & 63;     // 0..63 column group
    const int j0  = cgr * 8;
    const int b0  = bg * 8;

    const int jj  = tid >> 5;            // 0..7
    const int kc  = tid & 31;            // 0..31 K-chunk
    const int g_  = kc >> 3;             // my gate after reduce-scatter
    const int bb_ = kc & 7;              // my batch after reduce-scatter

    // t-invariant U slice: u[g][kk] = U[kc*16+kk][g*512 + j0 + jj]
    float u[4][16];
    #pragma unroll
    for (int g = 0; g < 4; ++g)
        #pragma unroll
        for (int kk = 0; kk < 16; ++kk)
            u[g][kk] = U[(size_t)(kc * 16 + kk) * G4_ + (g << 9) + j0 + jj];

    // swizzled-G per-thread offset for step t: base(t) + bb_*32 + g_*8 + jj
    const int gofs = bb_ * 32 + g_ * 8 + jj;
    float zpre = G[((size_t)(0 * 4 + bg) * 64 + cgr) * 256 + gofs];

    float c_reg = 0.f;
    unsigned* grp_bar = bar + bg * 64;   // 256B apart per group

    for (int t = 0; t < T_; ++t) {
        const float* hcur = hbuf + (t & 1) * (B_ * HID_);
        float*       hnxt = hbuf + ((t + 1) & 1) * (B_ * HID_);

        // ---- stage h[8][512] -> LDS (coherent loads, padded layout) ----
        {
            const float* p[4]; float* dst[4];
            #pragma unroll
            for (int q = 0; q < 4; ++q) {
                int idx = q * 256 + tid;
                int bL  = idx >> 7;          // 0..7
                int k4  = idx & 127;         // float4 index within row
                p[q]   = hcur + (b0 + bL) * HID_ + k4 * 4;
                dst[q] = &hlds[bL * 640 + (k4 >> 2) * 20 + (k4 & 3) * 4];
            }
            f32x4 v0, v1, v2, v3;
            load4_coherent(p[0], p[1], p[2], p[3], v0, v1, v2, v3);
            *(f32x4*)dst[0] = v0;
            *(f32x4*)dst[1] = v1;
            *(f32x4*)dst[2] = v2;
            *(f32x4*)dst[3] = v3;
        }
        __syncthreads();

        // prefetch next step's gate-pre (independent, hidden under compute)
        float zpre_next = 0.f;
        if (t + 1 < T_)
            zpre_next = G[((size_t)((t + 1) * 4 + bg) * 64 + cgr) * 256 + gofs];

        // ---- partial dot over my K-chunk: v[g*8+b] ----
        float v[32];
        #pragma unroll
        for (int s = 0; s < 32; ++s) v[s] = 0.f;

        #pragma unroll
        for (int bb = 0; bb < 8; ++bb) {
            const float* hp = &hlds[bb * 640 + kc * 20];
            f32x4 h0 = *(const f32x4*)(hp + 0);
            f32x4 h1 = *(const f32x4*)(hp + 4);
            f32x4 h2 = *(const f32x4*)(hp + 8);
            f32x4 h3 = *(const f32x4*)(hp + 12);
            const float hh[16] = {h0.x, h0.y, h0.z, h0.w,  h1.x, h1.y, h1.z, h1.w,
                                  h2.x, h2.y, h2.z, h2.w,  h3.x, h3.y, h3.z, h3.w};
            #pragma unroll
            for (int g = 0; g < 4; ++g)
                #pragma unroll
                for (int kk = 0; kk < 16; ++kk)
                    v[g * 8 + bb] += u[g][kk] * hh[kk];
        }

        // ---- reduce-scatter over the 32 kc lanes (width-32 partitions) ----
        float a16[16];
        #pragma unroll
        for (int i = 0; i < 16; ++i) {
            float keep = (kc & 16) ? v[i + 16] : v[i];
            float give = (kc & 16) ? v[i]      : v[i + 16];
            a16[i] = keep + __shfl_xor(give, 16, 32);
        }
        float a8[8];
        #pragma unroll
        for (int i = 0; i < 8; ++i) {
            float keep = (kc & 8) ? a16[i + 8] : a16[i];
            float give = (kc & 8) ? a16[i]     : a16[i + 8];
            a8[i] = keep + __shfl_xor(give, 8, 32);
        }
        float a4[4];
        #pragma unroll
        for (int i = 0; i < 4; ++i) {
            float keep = (kc & 4) ? a8[i + 4] : a8[i];
            float give = (kc & 4) ? a8[i]     : a8[i + 4];
            a4[i] = keep + __shfl_xor(give, 4, 32);
        }
        float a2[2];
        #pragma unroll
        for (int i = 0; i < 2; ++i) {
            float keep = (kc & 2) ? a4[i + 2] : a4[i];
            float give = (kc & 2) ? a4[i]     : a4[i + 2];
            a2[i] = keep + __shfl_xor(give, 2, 32);
        }
        float keep1 = (kc & 1) ? a2[1] : a2[0];
        float give1 = (kc & 1) ? a2[0] : a2[1];
        float z = keep1 + __shfl_xor(give1, 1, 32) + zpre;
        zpre = zpre_next;

        // ---- gate exchange: g0 lanes get (i,f,g,o) directly ----
        float z8  = __shfl_xor(z, 8, 32);
        float z16 = __shfl_xor(z, 16, 32);
        float z24 = __shfl_xor(z, 24, 32);
        // on g==0 lanes: z=i, z8=f, z16=g, z24=o  (others compute garbage)
        float i_ = fsigm(z);
        float f_ = fsigm(z8);
        float gg = ftanh(z16);
        float o_ = fsigm(z24);
        c_reg = f_ * c_reg + i_ * gg;
        float h_ = o_ * ftanh(c_reg);

        if (g_ == 0) {
            const int brow = b0 + bb_;
            store_coherent(&hnxt[brow * HID_ + j0 + jj], h_);              // -> IF$
            Hout[(size_t)t * (B_ * HID_) + brow * HID_ + j0 + jj] = h_;    // cached
        }

        // ---- per-group software barrier (64 blocks), RELAXED atomics ----
        if (t + 1 < T_) {
            __syncthreads();   // drains vmcnt: coherent h stores are at IF$ now
            if (tid == 0) {
                __hip_atomic_fetch_add(grp_bar, 1u,
                                       __ATOMIC_RELAXED, __HIP_MEMORY_SCOPE_AGENT);
                const unsigned target = (unsigned)(t + 1) * 64u;
                unsigned guard = 0;
                while (__hip_atomic_load(grp_bar,
                           __ATOMIC_RELAXED, __HIP_MEMORY_SCOPE_AGENT) < target) {
                    __builtin_amdgcn_s_sleep(1);
                    if (++guard > 50000000u) break;   // hang-safety
                }
            }
            __syncthreads();
        }
    }
}

// ---------------------------------------------------------------------------
extern "C" void kernel_launch(void* const* d_in, const int* in_sizes, int n_in,
                              void* d_out, int out_size, void* d_ws, size_t ws_size,
                              hipStream_t stream)
{
    const int*   tokens = (const int*)  d_in[0];
    const float* emb    = (const float*)d_in[1];
    const float* W0     = (const float*)d_in[2];
    const float* U0     = (const float*)d_in[3];
    const float* b0     = (const float*)d_in[4];
    const float* W1     = (const float*)d_in[5];
    const float* U1     = (const float*)d_in[6];
    const float* b1     = (const float*)d_in[7];
    const float* Wout   = (const float*)d_in[8];
    const float* bout   = (const float*)d_in[9];
    float* out = (float*)d_out;

    // G (8192x2048 fp32 = 64 MiB, swizzled layout) lives in d_out (312 MiB);
    // dead before the final GEMM overwrites all of d_out. d_ws ~16.2 MiB:
    float* ws   = (float*)d_ws;
    float*    H    = ws;                                   // 8192*512 fp32 (16 MiB)
    float*    hbuf = H + (size_t)8192 * 512;               // 2*32*512 ping-pong h
    unsigned* bar  = (unsigned*)(hbuf + 2 * B_ * HID_);    // barrier state
    float*    G    = out;                                  // 8192*2048 in d_out

    dim3 blk(256);

    // G = gather(emb,tokens) @ W0 + b0   (swizzled store)
    gemm_k<true, false, true><<<dim3(G4_ / 64, 8192 / 128), blk, 0, stream>>>(
        nullptr, W0, b0, G, 8192, G4_, 512, tokens, emb);

    // layer-0 recurrence -> H ([T,B,512])
    hipMemsetAsync(hbuf, 0, B_ * HID_ * sizeof(float), stream);  // h[0] = 0
    hipMemsetAsync(bar, 0, 1024 * sizeof(unsigned), stream);     // barrier = 0
    lstm_rec_k<<<dim3(NBLK_), blk, 0, stream>>>(G, U0, H, hbuf, bar);

    // G = H @ W1 + b1   (swizzled store)
    gemm_k<false, false, true><<<dim3(G4_ / 64, 8192 / 128), blk, 0, stream>>>(
        H, W1, b1, G, 8192, G4_, 512, nullptr, nullptr);

    // layer-1 recurrence -> H
    hipMemsetAsync(hbuf, 0, B_ * HID_ * sizeof(float), stream);
    hipMemsetAsync(bar, 0, 1024 * sizeof(unsigned), stream);
    lstm_rec_k<<<dim3(NBLK_), blk, 0, stream>>>(G, U1, H, hbuf, bar);

    // out[b*T+t, :] = H[t*B+b, :] @ W_out + b_out
    gemm_k<false, true, false><<<dim3((VOC_ + 63) / 64, 8192 / 128), blk, 0, stream>>>(
        H, Wout, bout, out, 8192, VOC_, 512, nullptr, nullptr);
}

// Round 5
// 3349.745 us; speedup vs baseline: 3.3693x; 1.0255x over previous
//
#include <hip/hip_runtime.h>
#include <math.h>

#define B_    32
#define T_    256
#define HID_  512
#define G4_   2048   // 4*HID
#define VOC_  10000
#define NPAD_ 10112  // 79*128, padded vocab for the bf16 GEMM
#define NBLK_ 256    // blocks in the persistent recurrence kernel

typedef float f32x4 __attribute__((ext_vector_type(4)));
typedef short bf16x8 __attribute__((ext_vector_type(8)));
typedef unsigned short u16;
typedef u16 u16x8 __attribute__((ext_vector_type(8)));

// ---------------- coherent (cross-XCD via IF$) helpers: sc0 sc1 ------------
__device__ __forceinline__ void load4_coherent(const float* p0, const float* p1,
                                               const float* p2, const float* p3,
                                               f32x4& a, f32x4& b, f32x4& c, f32x4& d)
{
    asm volatile(
        "global_load_dwordx4 %0, %4, off sc0 sc1\n\t"
        "global_load_dwordx4 %1, %5, off sc0 sc1\n\t"
        "global_load_dwordx4 %2, %6, off sc0 sc1\n\t"
        "global_load_dwordx4 %3, %7, off sc0 sc1\n\t"
        "s_waitcnt vmcnt(0)"
        : "=&v"(a), "=&v"(b), "=&v"(c), "=&v"(d)
        : "v"(p0), "v"(p1), "v"(p2), "v"(p3)
        : "memory");
}
__device__ __forceinline__ void store_coherent(float* p, float x)
{
    asm volatile("global_store_dword %0, %1, off sc0 sc1" :: "v"(p), "v"(x) : "memory");
}
__device__ __forceinline__ void store_coherent_u32(unsigned* p, unsigned x)
{
    asm volatile("global_store_dword %0, %1, off sc0 sc1" :: "v"(p), "v"(x) : "memory");
}
__device__ __forceinline__ unsigned load_coherent_u32(const unsigned* p)
{
    unsigned v;
    asm volatile("global_load_dword %0, %1, off sc0 sc1\n\ts_waitcnt vmcnt(0)"
                 : "=v"(v) : "v"(p) : "memory");
    return v;
}

__device__ __forceinline__ float fsigm(float x)
{
    float e = exp2f(x * -1.4426950408889634f);
    return __builtin_amdgcn_rcpf(1.f + e);
}
__device__ __forceinline__ float ftanh(float x)
{
    float e = exp2f(x * 2.8853900817779268f);
    return 1.f - 2.f * __builtin_amdgcn_rcpf(e + 1.f);
}

// fp32 -> bf16_hi + bf16_lo (RNE both; a ~= hi + lo with ~16 mantissa bits)
__device__ __forceinline__ void bsplit(float x, u16& hi, u16& lo)
{
    union { float f; unsigned u; } a; a.f = x;
    unsigned r = a.u + 0x7FFFu + ((a.u >> 16) & 1u);
    hi = (u16)(r >> 16);
    union { unsigned u; float f; } hf; hf.u = ((unsigned)hi) << 16;
    union { float f; unsigned u; } b; b.f = x - hf.f;
    unsigned r2 = b.u + 0x7FFFu + ((b.u >> 16) & 1u);
    lo = (u16)(r2 >> 16);
}

// ---------------------------------------------------------------------------
// Transpose + split: W [512][N] fp32  ->  WT_hi/lo [Npad][512] bf16 (n-major)
// 64x64 tiles; pad rows (n >= N) are zero.
// ---------------------------------------------------------------------------
__global__ __launch_bounds__(256)
void wsplit_k(const float* __restrict__ W, u16* __restrict__ Thi,
              u16* __restrict__ Tlo, int N)
{
    __shared__ float tile[64][68];
    const int tid = threadIdx.x;
    const int n0 = blockIdx.x * 64;
    const int k0 = blockIdx.y * 64;

    #pragma unroll
    for (int it = 0; it < 4; ++it) {
        int idx = it * 256 + tid;
        int kr = idx >> 4;
        int nc = (idx & 15) * 4;
        int n  = n0 + nc;
        float4 v = {0.f, 0.f, 0.f, 0.f};
        const float* wp = W + (size_t)(k0 + kr) * N + n;
        if (n + 3 < N) v = *(const float4*)wp;
        else {
            if (n + 0 < N) v.x = wp[0];
            if (n + 1 < N) v.y = wp[1];
            if (n + 2 < N) v.z = wp[2];
            if (n + 3 < N) v.w = wp[3];
        }
        tile[kr][nc + 0] = v.x; tile[kr][nc + 1] = v.y;
        tile[kr][nc + 2] = v.z; tile[kr][nc + 3] = v.w;
    }
    __syncthreads();

    #pragma unroll
    for (int it = 0; it < 2; ++it) {
        int idx = it * 256 + tid;
        int nr = idx >> 3;
        int kb = (idx & 7) * 8;
        u16x8 hv, lv;
        #pragma unroll
        for (int e = 0; e < 8; ++e) {
            u16 h, l;
            bsplit(tile[kb + e][nr], h, l);
            hv[e] = h; lv[e] = l;
        }
        size_t o = (size_t)(n0 + nr) * 512 + k0 + kb;
        *(u16x8*)(Thi + o) = hv;
        *(u16x8*)(Tlo + o) = lv;
    }
}

// ---------------------------------------------------------------------------
// Gather + split: A[r][:] = emb[tokens], r = t*32+b  ->  Ahi/Alo [8192][512]
// ---------------------------------------------------------------------------
__global__ __launch_bounds__(256)
void gather_split_k(const int* __restrict__ tokens, const float* __restrict__ emb,
                    u16* __restrict__ Ahi, u16* __restrict__ Alo)
{
    const int r    = blockIdx.x * 4 + (threadIdx.x >> 6);
    const int lane = threadIdx.x & 63;
    const int tok  = tokens[(r & 31) * T_ + (r >> 5)];
    const float* src = emb + (size_t)tok * 512 + lane * 8;
    float4 v0 = *(const float4*)(src);
    float4 v1 = *(const float4*)(src + 4);
    const float vv[8] = {v0.x, v0.y, v0.z, v0.w, v1.x, v1.y, v1.z, v1.w};
    u16x8 hv, lv;
    #pragma unroll
    for (int e = 0; e < 8; ++e) { u16 h, l; bsplit(vv[e], h, l); hv[e] = h; lv[e] = l; }
    size_t o = (size_t)r * 512 + lane * 8;
    *(u16x8*)(Ahi + o) = hv;
    *(u16x8*)(Alo + o) = lv;
}

// ---------------------------------------------------------------------------
// Split-bf16 MFMA GEMM: C[M=8192, N] = (Ahi+Alo)[M,512] @ (Bhi+Blo)^T + bias
//   3 K-segments (Ahi*Bhi, Ahi*Blo, Alo*Bhi) = effective K' 1536, BK=64.
// B given pre-transposed n-major: B*[n][k], n < Npad (pad rows zero).
// 128x128 tile, 4 waves (2x2), each wave 64x64 via 16x16x32 bf16 MFMA.
// LDS: XOR-swizzled (slot = kchunk ^ (row&7)) achieved by pre-swizzling the
// global source address; global_load_lds dest stays linear (wave base+lane*16).
// MODE 0: store fp32 G in recurrence-swizzled layout (N=2048), +bias.
// MODE 1: out[(r&31)*256 + (r>>5)][c] = acc + bias, guard c < VOC_ (N=NPAD_).
// ---------------------------------------------------------------------------
template<int MODE>
__global__ __launch_bounds__(256)
void gemm_bf16_k(const u16* __restrict__ Ahi, const u16* __restrict__ Alo,
                 const u16* __restrict__ Bhi, const u16* __restrict__ Blo,
                 const float* __restrict__ bias, float* __restrict__ C, int N)
{
    __shared__ u16 As[2][128 * 64];
    __shared__ u16 Bs[2][128 * 64];

    const int tid  = threadIdx.x;
    const int lane = tid & 63;
    const int wid  = tid >> 6;         // 0..3
    const int wm   = wid >> 1;         // 0..1
    const int wn   = wid & 1;          // 0..1
    const int m0   = blockIdx.y * 128;
    const int n0   = blockIdx.x * 128;

    f32x4 acc[4][4];
    #pragma unroll
    for (int i = 0; i < 4; ++i)
        #pragma unroll
        for (int j = 0; j < 4; ++j) acc[i][j] = (f32x4){0.f, 0.f, 0.f, 0.f};

    auto stage = [&](int s, int buf) {
        const int ksel = s >> 3;                 // 0,1,2
        const int koff = (s & 7) * 64;
        const u16* Asrc = (ksel == 2) ? Alo : Ahi;
        const u16* Bsrc = (ksel == 1) ? Blo : Bhi;
        #pragma unroll
        for (int q = 0; q < 4; ++q) {
            const int u   = q * 256 + tid;       // 16B unit index
            const int row = u >> 3;
            const int kch = (u & 7) ^ (row & 7); // pre-swizzled source chunk
            const u16* ga = Asrc + (size_t)(m0 + row) * 512 + koff + kch * 8;
            const u16* gb = Bsrc + (size_t)(n0 + row) * 512 + koff + kch * 8;
            u16* la = &As[buf][(q * 256 + wid * 64) * 8];   // wave-uniform base
            u16* lb = &Bs[buf][(q * 256 + wid * 64) * 8];
            __builtin_amdgcn_global_load_lds(
                (const __attribute__((address_space(1))) void*)ga,
                (__attribute__((address_space(3))) void*)la, 16, 0, 0);
            __builtin_amdgcn_global_load_lds(
                (const __attribute__((address_space(1))) void*)gb,
                (__attribute__((address_space(3))) void*)lb, 16, 0, 0);
        }
    };

    stage(0, 0);
    for (int s = 0; s < 24; ++s) {
        const int buf = s & 1;
        __syncthreads();                          // stage(s) landed (vmcnt drain)
        if (s + 1 < 24) stage(s + 1, buf ^ 1);    // async prefetch next tile

        #pragma unroll
        for (int q = 0; q < 2; ++q) {             // two K=32 slices of BK=64
            bf16x8 af[4], bfr[4];
            #pragma unroll
            for (int mt = 0; mt < 4; ++mt) {
                const int r    = wm * 64 + mt * 16 + (lane & 15);
                const int slot = (q * 4 + (lane >> 4)) ^ (r & 7);
                af[mt] = *(const bf16x8*)&As[buf][r * 64 + slot * 8];
            }
            #pragma unroll
            for (int nt = 0; nt < 4; ++nt) {
                const int rn   = wn * 64 + nt * 16 + (lane & 15);
                const int slot = (q * 4 + (lane >> 4)) ^ (rn & 7);
                bfr[nt] = *(const bf16x8*)&Bs[buf][rn * 64 + slot * 8];
            }
            #pragma unroll
            for (int mt = 0; mt < 4; ++mt)
                #pragma unroll
                for (int nt = 0; nt < 4; ++nt)
                    acc[mt][nt] = __builtin_amdgcn_mfma_f32_16x16x32_bf16(
                        af[mt], bfr[nt], acc[mt][nt], 0, 0, 0);
        }
    }

    // epilogue: C/D layout col=lane&15, row=(lane>>4)*4+reg  [guide-verified]
    #pragma unroll
    for (int mt = 0; mt < 4; ++mt) {
        #pragma unroll
        for (int nt = 0; nt < 4; ++nt) {
            const int c = n0 + wn * 64 + nt * 16 + (lane & 15);
            #pragma unroll
            for (int j = 0; j < 4; ++j) {
                const int r = m0 + wm * 64 + mt * 16 + (lane >> 4) * 4 + j;
                float val = acc[mt][nt][j];
                if constexpr (MODE == 0) {
                    val += bias[c];
                    const int t = r >> 5, bgrp = (r >> 3) & 3, bb = r & 7;
                    const int g = c >> 9, jblk = (c & 511) >> 3, jjs = c & 7;
                    C[(((size_t)t * 4 + bgrp) * 64 + jblk) * 256 + bb * 32 + g * 8 + jjs] = val;
                } else {
                    if (c < VOC_) {
                        val += bias[c];
                        const size_t orow = (size_t)(r & 31) * T_ + (r >> 5);
                        C[orow * VOC_ + c] = val;
                    }
                }
            }
        }
    }
}

// ---------------------------------------------------------------------------
// LSTM recurrence, persistent: 256 WGs x 256 thr, per-batch-group sync via
// contention-free flag vector: block stores flags[blk]=t+1 (coherent), wave 0
// polls its group's 64 flags with one 64-lane coherent load + __all.
// Thread (jj=tid>>5, kc=tid&31) owns K-chunk [kc*16,+16) for 4 gates x 8 b.
// h out is written directly as bf16 hi/lo (feeds the split-bf16 GEMMs).
// ---------------------------------------------------------------------------
__global__ __launch_bounds__(256, 1)
void lstm_rec_k(const float* __restrict__ G, const float* __restrict__ U,
                u16* __restrict__ Hhi, u16* __restrict__ Hlo,
                float* __restrict__ hbuf, unsigned* __restrict__ flags)
{
    __shared__ float hlds[8 * 640];      // [b][chunk kc: 16 floats + 4 pad]

    const int tid = threadIdx.x;
    const int bg  = blockIdx.x >> 6;     // 0..3  batch group
    const int cgr = blockIdx.x & 63;     // 0..63 column group
    const int j0  = cgr * 8;
    const int b0  = bg * 8;

    const int jj  = tid >> 5;            // 0..7
    const int kc  = tid & 31;            // 0..31 K-chunk
    const int g_  = kc >> 3;             // my gate after reduce-scatter
    const int bb_ = kc & 7;              // my batch after reduce-scatter

    float u[4][16];
    #pragma unroll
    for (int g = 0; g < 4; ++g)
        #pragma unroll
        for (int kk = 0; kk < 16; ++kk)
            u[g][kk] = U[(size_t)(kc * 16 + kk) * G4_ + (g << 9) + j0 + jj];

    const int gofs = bb_ * 32 + g_ * 8 + jj;
    float zpre = G[((size_t)bg * 64 + cgr) * 256 + gofs];

    float c_reg = 0.f;

    for (int t = 0; t < T_; ++t) {
        const float* hcur = hbuf + (t & 1) * (B_ * HID_);
        float*       hnxt = hbuf + ((t + 1) & 1) * (B_ * HID_);

        // stage h[8][512] -> LDS (coherent, padded layout)
        {
            const float* p[4]; float* dst[4];
            #pragma unroll
            for (int q = 0; q < 4; ++q) {
                int idx = q * 256 + tid;
                int bL  = idx >> 7;
                int k4  = idx & 127;
                p[q]   = hcur + (b0 + bL) * HID_ + k4 * 4;
                dst[q] = &hlds[bL * 640 + (k4 >> 2) * 20 + (k4 & 3) * 4];
            }
            f32x4 v0, v1, v2, v3;
            load4_coherent(p[0], p[1], p[2], p[3], v0, v1, v2, v3);
            *(f32x4*)dst[0] = v0;
            *(f32x4*)dst[1] = v1;
            *(f32x4*)dst[2] = v2;
            *(f32x4*)dst[3] = v3;
        }
        __syncthreads();

        float zpre_next = 0.f;
        if (t + 1 < T_)
            zpre_next = G[((size_t)((t + 1) * 4 + bg) * 64 + cgr) * 256 + gofs];

        float v[32];
        #pragma unroll
        for (int s = 0; s < 32; ++s) v[s] = 0.f;

        #pragma unroll
        for (int bb = 0; bb < 8; ++bb) {
            const float* hp = &hlds[bb * 640 + kc * 20];
            f32x4 h0 = *(const f32x4*)(hp + 0);
            f32x4 h1 = *(const f32x4*)(hp + 4);
            f32x4 h2 = *(const f32x4*)(hp + 8);
            f32x4 h3 = *(const f32x4*)(hp + 12);
            const float hh[16] = {h0.x, h0.y, h0.z, h0.w,  h1.x, h1.y, h1.z, h1.w,
                                  h2.x, h2.y, h2.z, h2.w,  h3.x, h3.y, h3.z, h3.w};
            #pragma unroll
            for (int g = 0; g < 4; ++g)
                #pragma unroll
                for (int kk = 0; kk < 16; ++kk)
                    v[g * 8 + bb] += u[g][kk] * hh[kk];
        }

        // reduce-scatter over 32 kc lanes
        float a16[16];
        #pragma unroll
        for (int i = 0; i < 16; ++i) {
            float keep = (kc & 16) ? v[i + 16] : v[i];
            float give = (kc & 16) ? v[i]      : v[i + 16];
            a16[i] = keep + __shfl_xor(give, 16, 32);
        }
        float a8[8];
        #pragma unroll
        for (int i = 0; i < 8; ++i) {
            float keep = (kc & 8) ? a16[i + 8] : a16[i];
            float give = (kc & 8) ? a16[i]     : a16[i + 8];
            a8[i] = keep + __shfl_xor(give, 8, 32);
        }
        float a4[4];
        #pragma unroll
        for (int i = 0; i < 4; ++i) {
            float keep = (kc & 4) ? a8[i + 4] : a8[i];
            float give = (kc & 4) ? a8[i]     : a8[i + 4];
            a4[i] = keep + __shfl_xor(give, 4, 32);
        }
        float a2[2];
        #pragma unroll
        for (int i = 0; i < 2; ++i) {
            float keep = (kc & 2) ? a4[i + 2] : a4[i];
            float give = (kc & 2) ? a4[i]     : a4[i + 2];
            a2[i] = keep + __shfl_xor(give, 2, 32);
        }
        float keep1 = (kc & 1) ? a2[1] : a2[0];
        float give1 = (kc & 1) ? a2[0] : a2[1];
        float z = keep1 + __shfl_xor(give1, 1, 32) + zpre;
        zpre = zpre_next;

        float z8  = __shfl_xor(z, 8, 32);
        float z16 = __shfl_xor(z, 16, 32);
        float z24 = __shfl_xor(z, 24, 32);
        float i_ = fsigm(z);
        float f_ = fsigm(z8);
        float gg = ftanh(z16);
        float o_ = fsigm(z24);
        c_reg = f_ * c_reg + i_ * gg;
        float h_ = o_ * ftanh(c_reg);

        if (g_ == 0) {
            const int brow = b0 + bb_;
            store_coherent(&hnxt[brow * HID_ + j0 + jj], h_);      // -> IF$
            u16 hi, lo; bsplit(h_, hi, lo);
            const size_t o = ((size_t)t * B_ + brow) * HID_ + j0 + jj;
            Hhi[o] = hi;                                           // cached
            Hlo[o] = lo;
        }

        // ---- per-group flag barrier (contention-free) ----
        if (t + 1 < T_) {
            __syncthreads();   // drains vmcnt: h stores at IF$
            if (tid < 64) {
                if (tid == 0)
                    store_coherent_u32(&flags[blockIdx.x], (unsigned)(t + 1));
                unsigned guard = 0;
                for (;;) {
                    unsigned f = load_coherent_u32(&flags[bg * 64 + tid]);
                    if (__all(f > (unsigned)t)) break;
                    if (++guard > 100000000u) break;   // hang-safety
                }
            }
            __syncthreads();
        }
    }
}

// ---------------------------------------------------------------------------
extern "C" void kernel_launch(void* const* d_in, const int* in_sizes, int n_in,
                              void* d_out, int out_size, void* d_ws, size_t ws_size,
                              hipStream_t stream)
{
    const int*   tokens = (const int*)  d_in[0];
    const float* emb    = (const float*)d_in[1];
    const float* W0     = (const float*)d_in[2];
    const float* U0     = (const float*)d_in[3];
    const float* b0     = (const float*)d_in[4];
    const float* W1     = (const float*)d_in[5];
    const float* U1     = (const float*)d_in[6];
    const float* b1     = (const float*)d_in[7];
    const float* Wout   = (const float*)d_in[8];
    const float* bout   = (const float*)d_in[9];
    float* out = (float*)d_out;

    // G (8192x2048 fp32, swizzled) lives in d_out (312 MiB; dead before the
    // final GEMM overwrites it). ws holds the bf16 operands (~46 MiB).
    u16* ws16 = (u16*)d_ws;
    size_t o = 0;
    u16* Ahi   = ws16 + o; o += (size_t)8192 * 512;
    u16* Alo   = ws16 + o; o += (size_t)8192 * 512;
    u16* W0Thi = ws16 + o; o += (size_t)G4_ * 512;
    u16* W0Tlo = ws16 + o; o += (size_t)G4_ * 512;
    u16* W1Thi = ws16 + o; o += (size_t)G4_ * 512;
    u16* W1Tlo = ws16 + o; o += (size_t)G4_ * 512;
    u16* WoThi = ws16 + o; o += (size_t)NPAD_ * 512;
    u16* WoTlo = ws16 + o; o += (size_t)NPAD_ * 512;
    float*    hbuf  = (float*)(ws16 + o);
    unsigned* flags = (unsigned*)(hbuf + 2 * B_ * HID_);
    float*    G     = out;

    dim3 blk(256);

    // weight transpose+split and embedding gather+split
    wsplit_k<<<dim3(G4_ / 64, 8), blk, 0, stream>>>(W0, W0Thi, W0Tlo, G4_);
    wsplit_k<<<dim3(G4_ / 64, 8), blk, 0, stream>>>(W1, W1Thi, W1Tlo, G4_);
    wsplit_k<<<dim3(NPAD_ / 64, 8), blk, 0, stream>>>(Wout, WoThi, WoTlo, VOC_);
    gather_split_k<<<dim3(2048), blk, 0, stream>>>(tokens, emb, Ahi, Alo);

    // G = X0 @ W0 + b0   (split-bf16 MFMA, swizzled store)
    gemm_bf16_k<0><<<dim3(G4_ / 128, 64), blk, 0, stream>>>(
        Ahi, Alo, W0Thi, W0Tlo, b0, G, G4_);

    // layer-0 recurrence -> Ahi/Alo (bf16 h)
    hipMemsetAsync(hbuf, 0, B_ * HID_ * sizeof(float), stream);
    hipMemsetAsync(flags, 0, NBLK_ * sizeof(unsigned), stream);
    lstm_rec_k<<<dim3(NBLK_), blk, 0, stream>>>(G, U0, Ahi, Alo, hbuf, flags);

    // G = H0 @ W1 + b1
    gemm_bf16_k<0><<<dim3(G4_ / 128, 64), blk, 0, stream>>>(
        Ahi, Alo, W1Thi, W1Tlo, b1, G, G4_);

    // layer-1 recurrence -> Ahi/Alo
    hipMemsetAsync(hbuf, 0, B_ * HID_ * sizeof(float), stream);
    hipMemsetAsync(flags, 0, NBLK_ * sizeof(unsigned), stream);
    lstm_rec_k<<<dim3(NBLK_), blk, 0, stream>>>(G, U1, Ahi, Alo, hbuf, flags);

    // out[b*T+t, :] = H1 @ W_out + b_out
    gemm_bf16_k<1><<<dim3(NPAD_ / 128, 64), blk, 0, stream>>>(
        Ahi, Alo, WoThi, WoTlo, bout, out, NPAD_);
}

// Round 6
// 2214.836 us; speedup vs baseline: 5.0958x; 1.5124x over previous
//
#include <hip/hip_runtime.h>
#include <math.h>

#define B_    32
#define T_    256
#define HID_  512
#define G4_   2048   // 4*HID
#define VOC_  10000
#define NPAD_ 10112  // 79*128, padded vocab for the bf16 GEMM

typedef float f32x4 __attribute__((ext_vector_type(4)));
typedef short bf16x8 __attribute__((ext_vector_type(8)));
typedef unsigned short u16;
typedef u16 u16x8 __attribute__((ext_vector_type(8)));

#define AADD(p)  __hip_atomic_fetch_add((p), 1u, __ATOMIC_RELAXED, __HIP_MEMORY_SCOPE_AGENT)
#define ALOAD(p) __hip_atomic_load((p), __ATOMIC_RELAXED, __HIP_MEMORY_SCOPE_AGENT)

// ---------------- coherent (cross-XCD via IF$) helpers: sc0 sc1 ------------
__device__ __forceinline__ void load4_coherent(const float* p0, const float* p1,
                                               const float* p2, const float* p3,
                                               f32x4& a, f32x4& b, f32x4& c, f32x4& d)
{
    asm volatile(
        "global_load_dwordx4 %0, %4, off sc0 sc1\n\t"
        "global_load_dwordx4 %1, %5, off sc0 sc1\n\t"
        "global_load_dwordx4 %2, %6, off sc0 sc1\n\t"
        "global_load_dwordx4 %3, %7, off sc0 sc1\n\t"
        "s_waitcnt vmcnt(0)"
        : "=&v"(a), "=&v"(b), "=&v"(c), "=&v"(d)
        : "v"(p0), "v"(p1), "v"(p2), "v"(p3)
        : "memory");
}
__device__ __forceinline__ void store_coherent(float* p, float x)
{
    asm volatile("global_store_dword %0, %1, off sc0 sc1" :: "v"(p), "v"(x) : "memory");
}

__device__ __forceinline__ float fsigm(float x)
{
    float e = exp2f(x * -1.4426950408889634f);
    return __builtin_amdgcn_rcpf(1.f + e);
}
__device__ __forceinline__ float ftanh(float x)
{
    float e = exp2f(x * 2.8853900817779268f);
    return 1.f - 2.f * __builtin_amdgcn_rcpf(e + 1.f);
}

// fp32 -> bf16_hi + bf16_lo (RNE both; a ~= hi + lo with ~16 mantissa bits)
__device__ __forceinline__ void bsplit(float x, u16& hi, u16& lo)
{
    union { float f; unsigned u; } a; a.f = x;
    unsigned r = a.u + 0x7FFFu + ((a.u >> 16) & 1u);
    hi = (u16)(r >> 16);
    union { unsigned u; float f; } hf; hf.u = ((unsigned)hi) << 16;
    union { float f; unsigned u; } b; b.f = x - hf.f;
    unsigned r2 = b.u + 0x7FFFu + ((b.u >> 16) & 1u);
    lo = (u16)(r2 >> 16);
}

// spin until *p >= tgt (monotonic counter), with hang-safety bail
__device__ __forceinline__ void wait_ge(unsigned* p, unsigned tgt)
{
    unsigned g = 0;
    while (ALOAD(p) < tgt) {
        __builtin_amdgcn_s_sleep(2);
        if (++g > 100000000u) break;
    }
}

// ---------------------------------------------------------------------------
// Transpose + split: W [512][N] fp32 -> WT_hi/lo [Npad][512] bf16 (n-major)
// ---------------------------------------------------------------------------
__global__ __launch_bounds__(256)
void wsplit_k(const float* __restrict__ W, u16* __restrict__ Thi,
              u16* __restrict__ Tlo, int N)
{
    __shared__ float tile[64][68];
    const int tid = threadIdx.x;
    const int n0 = blockIdx.x * 64;
    const int k0 = blockIdx.y * 64;

    #pragma unroll
    for (int it = 0; it < 4; ++it) {
        int idx = it * 256 + tid;
        int kr = idx >> 4;
        int nc = (idx & 15) * 4;
        int n  = n0 + nc;
        float4 v = {0.f, 0.f, 0.f, 0.f};
        const float* wp = W + (size_t)(k0 + kr) * N + n;
        if (n + 3 < N) v = *(const float4*)wp;
        else {
            if (n + 0 < N) v.x = wp[0];
            if (n + 1 < N) v.y = wp[1];
            if (n + 2 < N) v.z = wp[2];
            if (n + 3 < N) v.w = wp[3];
        }
        tile[kr][nc + 0] = v.x; tile[kr][nc + 1] = v.y;
        tile[kr][nc + 2] = v.z; tile[kr][nc + 3] = v.w;
    }
    __syncthreads();

    #pragma unroll
    for (int it = 0; it < 2; ++it) {
        int idx = it * 256 + tid;
        int nr = idx >> 3;
        int kb = (idx & 7) * 8;
        u16x8 hv, lv;
        #pragma unroll
        for (int e = 0; e < 8; ++e) {
            u16 h, l;
            bsplit(tile[kb + e][nr], h, l);
            hv[e] = h; lv[e] = l;
        }
        size_t o = (size_t)(n0 + nr) * 512 + k0 + kb;
        *(u16x8*)(Thi + o) = hv;
        *(u16x8*)(Tlo + o) = lv;
    }
}

// ---------------------------------------------------------------------------
// Gather + split: A[r][:] = emb[tokens], r = t*32+b -> Ahi/Alo [8192][512]
// ---------------------------------------------------------------------------
__global__ __launch_bounds__(256)
void gather_split_k(const int* __restrict__ tokens, const float* __restrict__ emb,
                    u16* __restrict__ Ahi, u16* __restrict__ Alo)
{
    const int r    = blockIdx.x * 4 + (threadIdx.x >> 6);
    const int lane = threadIdx.x & 63;
    const int tok  = tokens[(r & 31) * T_ + (r >> 5)];
    const float* src = emb + (size_t)tok * 512 + lane * 8;
    float4 v0 = *(const float4*)(src);
    float4 v1 = *(const float4*)(src + 4);
    const float vv[8] = {v0.x, v0.y, v0.z, v0.w, v1.x, v1.y, v1.z, v1.w};
    u16x8 hv, lv;
    #pragma unroll
    for (int e = 0; e < 8; ++e) { u16 h, l; bsplit(vv[e], h, l); hv[e] = h; lv[e] = l; }
    size_t o = (size_t)r * 512 + lane * 8;
    *(u16x8*)(Ahi + o) = hv;
    *(u16x8*)(Alo + o) = lv;
}

// ---------------------------------------------------------------------------
// Split-bf16 MFMA GEMM (unchanged from round 5; proven ~530us all-in)
// ---------------------------------------------------------------------------
template<int MODE>
__global__ __launch_bounds__(256)
void gemm_bf16_k(const u16* __restrict__ Ahi, const u16* __restrict__ Alo,
                 const u16* __restrict__ Bhi, const u16* __restrict__ Blo,
                 const float* __restrict__ bias, float* __restrict__ C, int N)
{
    __shared__ u16 As[2][128 * 64];
    __shared__ u16 Bs[2][128 * 64];

    const int tid  = threadIdx.x;
    const int lane = tid & 63;
    const int wid  = tid >> 6;
    const int wm   = wid >> 1;
    const int wn   = wid & 1;
    const int m0   = blockIdx.y * 128;
    const int n0   = blockIdx.x * 128;

    f32x4 acc[4][4];
    #pragma unroll
    for (int i = 0; i < 4; ++i)
        #pragma unroll
        for (int j = 0; j < 4; ++j) acc[i][j] = (f32x4){0.f, 0.f, 0.f, 0.f};

    auto stage = [&](int s, int buf) {
        const int ksel = s >> 3;
        const int koff = (s & 7) * 64;
        const u16* Asrc = (ksel == 2) ? Alo : Ahi;
        const u16* Bsrc = (ksel == 1) ? Blo : Bhi;
        #pragma unroll
        for (int q = 0; q < 4; ++q) {
            const int u   = q * 256 + tid;
            const int row = u >> 3;
            const int kch = (u & 7) ^ (row & 7);
            const u16* ga = Asrc + (size_t)(m0 + row) * 512 + koff + kch * 8;
            const u16* gb = Bsrc + (size_t)(n0 + row) * 512 + koff + kch * 8;
            u16* la = &As[buf][(q * 256 + wid * 64) * 8];
            u16* lb = &Bs[buf][(q * 256 + wid * 64) * 8];
            __builtin_amdgcn_global_load_lds(
                (const __attribute__((address_space(1))) void*)ga,
                (__attribute__((address_space(3))) void*)la, 16, 0, 0);
            __builtin_amdgcn_global_load_lds(
                (const __attribute__((address_space(1))) void*)gb,
                (__attribute__((address_space(3))) void*)lb, 16, 0, 0);
        }
    };

    stage(0, 0);
    for (int s = 0; s < 24; ++s) {
        const int buf = s & 1;
        __syncthreads();
        if (s + 1 < 24) stage(s + 1, buf ^ 1);

        #pragma unroll
        for (int q = 0; q < 2; ++q) {
            bf16x8 af[4], bfr[4];
            #pragma unroll
            for (int mt = 0; mt < 4; ++mt) {
                const int r    = wm * 64 + mt * 16 + (lane & 15);
                const int slot = (q * 4 + (lane >> 4)) ^ (r & 7);
                af[mt] = *(const bf16x8*)&As[buf][r * 64 + slot * 8];
            }
            #pragma unroll
            for (int nt = 0; nt < 4; ++nt) {
                const int rn   = wn * 64 + nt * 16 + (lane & 15);
                const int slot = (q * 4 + (lane >> 4)) ^ (rn & 7);
                bfr[nt] = *(const bf16x8*)&Bs[buf][rn * 64 + slot * 8];
            }
            #pragma unroll
            for (int mt = 0; mt < 4; ++mt)
                #pragma unroll
                for (int nt = 0; nt < 4; ++nt)
                    acc[mt][nt] = __builtin_amdgcn_mfma_f32_16x16x32_bf16(
                        af[mt], bfr[nt], acc[mt][nt], 0, 0, 0);
        }
    }

    #pragma unroll
    for (int mt = 0; mt < 4; ++mt) {
        #pragma unroll
        for (int nt = 0; nt < 4; ++nt) {
            const int c = n0 + wn * 64 + nt * 16 + (lane & 15);
            #pragma unroll
            for (int j = 0; j < 4; ++j) {
                const int r = m0 + wm * 64 + mt * 16 + (lane >> 4) * 4 + j;
                float val = acc[mt][nt][j];
                if constexpr (MODE == 0) {
                    val += bias[c];
                    const int t = r >> 5, bgrp = (r >> 3) & 3, bb = r & 7;
                    const int g = c >> 9, jblk = (c & 511) >> 3, jjs = c & 7;
                    C[(((size_t)t * 4 + bgrp) * 64 + jblk) * 256 + bb * 32 + g * 8 + jjs] = val;
                } else {
                    if (c < VOC_) {
                        val += bias[c];
                        const size_t orow = (size_t)(r & 31) * T_ + (r >> 5);
                        C[orow * VOC_ + c] = val;
                    }
                }
            }
        }
    }
}

// ---------------------------------------------------------------------------
// FUSED 2-layer LSTM recurrence, persistent: 512 blocks x 256 thr (2/CU).
// Blocks 0..255   = LAYER 0: per step, z0 = G[t] + h0@U0; publishes h0(t) to
//                   full fp32 history H0x[t+1] via IF$; shard+root arrival.
// Blocks 256..511 = LAYER 1: step t gates on bar0root >= 4(t+1) (h0(t) ready)
//                   and own bar1root >= 4t; z1 = x@W1 + h1@U1 + b1 computed as
//                   one concatenated K=1024 dot (u[4][32] regs, t-invariant);
//                   emits h1 bf16 hi/lo (feeds the final GEMM).
// Layer 0 never waits on layer 1 => deadlock-free even without co-residency.
// Barriers: relaxed agent atomics, 4 shards x 16 blocks + root per group
// (round-4-proven mechanism, narrowed to 64-block groups).
// ---------------------------------------------------------------------------
__global__ __launch_bounds__(256, 2)
void fused_rec_k(const float* __restrict__ G, const float* __restrict__ U0,
                 const float* __restrict__ W1, const float* __restrict__ U1,
                 const float* __restrict__ b1,
                 float* __restrict__ H0x,      // [T+1][32][512], slot0 zeroed
                 u16* __restrict__ Ahi, u16* __restrict__ Alo,
                 float* __restrict__ h1buf,    // [2][32][512], slot0 zeroed
                 unsigned* __restrict__ bar)
{
    __shared__ float lds[8 * 1152];      // L0 uses [8][640]; L1 uses [8][32][36]

    const int tid  = threadIdx.x;
    const int role = blockIdx.x >> 8;    // 0 = layer0, 1 = layer1
    const int blk  = blockIdx.x & 255;
    const int bg   = blk >> 6;           // 0..3  batch group
    const int cgr  = blk & 63;           // 0..63 column group
    const int j0   = cgr * 8;
    const int b0   = bg * 8;

    const int jj  = tid >> 5;            // 0..7
    const int kc  = tid & 31;            // 0..31 K-chunk
    const int g_  = kc >> 3;             // gate after reduce-scatter
    const int bb_ = kc & 7;              // batch after reduce-scatter
    const int shard = cgr & 3;

    // barrier pointers: shards 64B apart, roots separate
    unsigned* shard0 = bar + (bg * 4 + shard) * 16;
    unsigned* root0  = bar + 256 + bg * 16;
    unsigned* shard1 = bar + 512 + (bg * 4 + shard) * 16;
    unsigned* root1  = bar + 768 + bg * 16;

    if (role == 0) {
        // ---------------- LAYER 0 ----------------
        float u[4][16];
        #pragma unroll
        for (int g = 0; g < 4; ++g)
            #pragma unroll
            for (int kk = 0; kk < 16; ++kk)
                u[g][kk] = U0[(size_t)(kc * 16 + kk) * G4_ + (g << 9) + j0 + jj];

        const int gofs = bb_ * 32 + g_ * 8 + jj;
        float zpre = G[((size_t)bg * 64 + cgr) * 256 + gofs];
        float c_reg = 0.f;

        for (int t = 0; t < T_; ++t) {
            if (tid == 0 && t > 0) wait_ge(root0, 4u * (unsigned)t);
            __syncthreads();                       // SYNC_A: h0(t) ready, lds free

            // stage h0(t)=H0x[t] [8][512] -> lds (stride-20 padded)
            {
                const float* p[4]; float* dst[4];
                const float* hcur = H0x + (size_t)t * (B_ * HID_);
                #pragma unroll
                for (int q = 0; q < 4; ++q) {
                    int idx = q * 256 + tid;
                    int bL  = idx >> 7;
                    int k4  = idx & 127;
                    p[q]   = hcur + (b0 + bL) * HID_ + k4 * 4;
                    dst[q] = &lds[bL * 640 + (k4 >> 2) * 20 + (k4 & 3) * 4];
                }
                f32x4 v0, v1, v2, v3;
                load4_coherent(p[0], p[1], p[2], p[3], v0, v1, v2, v3);
                *(f32x4*)dst[0] = v0; *(f32x4*)dst[1] = v1;
                *(f32x4*)dst[2] = v2; *(f32x4*)dst[3] = v3;
            }
            __syncthreads();                       // SYNC_B

            float zpre_next = 0.f;
            if (t + 1 < T_)
                zpre_next = G[((size_t)((t + 1) * 4 + bg) * 64 + cgr) * 256 + gofs];

            float v[32];
            #pragma unroll
            for (int s = 0; s < 32; ++s) v[s] = 0.f;
            #pragma unroll
            for (int bb = 0; bb < 8; ++bb) {
                const float* hp = &lds[bb * 640 + kc * 20];
                f32x4 h0v = *(const f32x4*)(hp + 0);
                f32x4 h1v = *(const f32x4*)(hp + 4);
                f32x4 h2v = *(const f32x4*)(hp + 8);
                f32x4 h3v = *(const f32x4*)(hp + 12);
                const float hh[16] = {h0v.x, h0v.y, h0v.z, h0v.w, h1v.x, h1v.y, h1v.z, h1v.w,
                                      h2v.x, h2v.y, h2v.z, h2v.w, h3v.x, h3v.y, h3v.z, h3v.w};
                #pragma unroll
                for (int g = 0; g < 4; ++g)
                    #pragma unroll
                    for (int kk = 0; kk < 16; ++kk)
                        v[g * 8 + bb] += u[g][kk] * hh[kk];
            }

            // reduce-scatter over 32 kc lanes
            float a16[16];
            #pragma unroll
            for (int i = 0; i < 16; ++i) {
                float keep = (kc & 16) ? v[i + 16] : v[i];
                float give = (kc & 16) ? v[i]      : v[i + 16];
                a16[i] = keep + __shfl_xor(give, 16, 32);
            }
            float a8[8];
            #pragma unroll
            for (int i = 0; i < 8; ++i) {
                float keep = (kc & 8) ? a16[i + 8] : a16[i];
                float give = (kc & 8) ? a16[i]     : a16[i + 8];
                a8[i] = keep + __shfl_xor(give, 8, 32);
            }
            float a4[4];
            #pragma unroll
            for (int i = 0; i < 4; ++i) {
                float keep = (kc & 4) ? a8[i + 4] : a8[i];
                float give = (kc & 4) ? a8[i]     : a8[i + 4];
                a4[i] = keep + __shfl_xor(give, 4, 32);
            }
            float a2[2];
            #pragma unroll
            for (int i = 0; i < 2; ++i) {
                float keep = (kc & 2) ? a4[i + 2] : a4[i];
                float give = (kc & 2) ? a4[i]     : a4[i + 2];
                a2[i] = keep + __shfl_xor(give, 2, 32);
            }
            float keep1 = (kc & 1) ? a2[1] : a2[0];
            float give1 = (kc & 1) ? a2[0] : a2[1];
            float z = keep1 + __shfl_xor(give1, 1, 32) + zpre;
            zpre = zpre_next;

            float z8  = __shfl_xor(z, 8, 32);
            float z16 = __shfl_xor(z, 16, 32);
            float z24 = __shfl_xor(z, 24, 32);
            float i_ = fsigm(z);
            float f_ = fsigm(z8);
            float gg = ftanh(z16);
            float o_ = fsigm(z24);
            c_reg = f_ * c_reg + i_ * gg;
            float h_ = o_ * ftanh(c_reg);

            if (g_ == 0)
                store_coherent(&H0x[(size_t)(t + 1) * (B_ * HID_)
                                    + (b0 + bb_) * HID_ + j0 + jj], h_);

            __syncthreads();                       // SYNC_C: stores drained
            if (tid == 0) {
                unsigned old = AADD(shard0);
                if (old + 1u == 16u * (unsigned)(t + 1)) AADD(root0);
            }
        }
    } else {
        // ---------------- LAYER 1 ----------------
        // concatenated K=1024: kc<16 -> W1 rows (x part), kc>=16 -> U1 (h part)
        float u[4][32];
        #pragma unroll
        for (int g = 0; g < 4; ++g)
            #pragma unroll
            for (int kk = 0; kk < 32; ++kk) {
                const int K = kc * 32 + kk;
                u[g][kk] = (K < 512)
                    ? W1[(size_t)K * G4_ + (g << 9) + j0 + jj]
                    : U1[(size_t)(K - 512) * G4_ + (g << 9) + j0 + jj];
            }
        const float zb = b1[(g_ << 9) + j0 + jj];
        float c_reg = 0.f;

        for (int t = 0; t < T_; ++t) {
            if (tid == 0) {
                wait_ge(root0, 4u * (unsigned)(t + 1));          // h0(t) ready
                if (t > 0) wait_ge(root1, 4u * (unsigned)t);     // h1(t) ready
            }
            __syncthreads();                       // SYNC_A

            // stage [x=h0(t) | h1(t)] [8][1024] -> lds[b][kc][36]
            {
                const float* xbase = H0x  + (size_t)(t + 1) * (B_ * HID_);
                const float* hbase = h1buf + (size_t)(t & 1) * (B_ * HID_);
                const float* p[8]; float* dst[8];
                const int k = tid * 4;             // 0..1020
                #pragma unroll
                for (int q = 0; q < 8; ++q) {
                    p[q] = (k < 512) ? (xbase + (b0 + q) * HID_ + k)
                                     : (hbase + (b0 + q) * HID_ + (k - 512));
                    dst[q] = &lds[q * 1152 + (tid >> 3) * 36 + (tid & 7) * 4];
                }
                f32x4 v0, v1, v2, v3, v4, v5, v6, v7;
                load4_coherent(p[0], p[1], p[2], p[3], v0, v1, v2, v3);
                load4_coherent(p[4], p[5], p[6], p[7], v4, v5, v6, v7);
                *(f32x4*)dst[0] = v0; *(f32x4*)dst[1] = v1;
                *(f32x4*)dst[2] = v2; *(f32x4*)dst[3] = v3;
                *(f32x4*)dst[4] = v4; *(f32x4*)dst[5] = v5;
                *(f32x4*)dst[6] = v6; *(f32x4*)dst[7] = v7;
            }
            __syncthreads();                       // SYNC_B

            float v[32];
            #pragma unroll
            for (int s = 0; s < 32; ++s) v[s] = 0.f;
            #pragma unroll
            for (int bb = 0; bb < 8; ++bb) {
                const float* hp = &lds[bb * 1152 + kc * 36];
                #pragma unroll
                for (int half = 0; half < 2; ++half) {
                    f32x4 h0v = *(const f32x4*)(hp + half * 16 + 0);
                    f32x4 h1v = *(const f32x4*)(hp + half * 16 + 4);
                    f32x4 h2v = *(const f32x4*)(hp + half * 16 + 8);
                    f32x4 h3v = *(const f32x4*)(hp + half * 16 + 12);
                    const float hh[16] = {h0v.x, h0v.y, h0v.z, h0v.w, h1v.x, h1v.y, h1v.z, h1v.w,
                                          h2v.x, h2v.y, h2v.z, h2v.w, h3v.x, h3v.y, h3v.z, h3v.w};
                    #pragma unroll
                    for (int g = 0; g < 4; ++g)
                        #pragma unroll
                        for (int kk = 0; kk < 16; ++kk)
                            v[g * 8 + bb] += u[g][half * 16 + kk] * hh[kk];
                }
            }

            float a16[16];
            #pragma unroll
            for (int i = 0; i < 16; ++i) {
                float keep = (kc & 16) ? v[i + 16] : v[i];
                float give = (kc & 16) ? v[i]      : v[i + 16];
                a16[i] = keep + __shfl_xor(give, 16, 32);
            }
            float a8[8];
            #pragma unroll
            for (int i = 0; i < 8; ++i) {
                float keep = (kc & 8) ? a16[i + 8] : a16[i];
                float give = (kc & 8) ? a16[i]     : a16[i + 8];
                a8[i] = keep + __shfl_xor(give, 8, 32);
            }
            float a4[4];
            #pragma unroll
            for (int i = 0; i < 4; ++i) {
                float keep = (kc & 4) ? a8[i + 4] : a8[i];
                float give = (kc & 4) ? a8[i]     : a8[i + 4];
                a4[i] = keep + __shfl_xor(give, 4, 32);
            }
            float a2[2];
            #pragma unroll
            for (int i = 0; i < 2; ++i) {
                float keep = (kc & 2) ? a4[i + 2] : a4[i];
                float give = (kc & 2) ? a4[i]     : a4[i + 2];
                a2[i] = keep + __shfl_xor(give, 2, 32);
            }
            float keep1 = (kc & 1) ? a2[1] : a2[0];
            float give1 = (kc & 1) ? a2[0] : a2[1];
            float z = keep1 + __shfl_xor(give1, 1, 32) + zb;

            float z8  = __shfl_xor(z, 8, 32);
            float z16 = __shfl_xor(z, 16, 32);
            float z24 = __shfl_xor(z, 24, 32);
            float i_ = fsigm(z);
            float f_ = fsigm(z8);
            float gg = ftanh(z16);
            float o_ = fsigm(z24);
            c_reg = f_ * c_reg + i_ * gg;
            float h_ = o_ * ftanh(c_reg);

            if (g_ == 0) {
                const int brow = b0 + bb_;
                store_coherent(&h1buf[(size_t)((t + 1) & 1) * (B_ * HID_)
                                      + brow * HID_ + j0 + jj], h_);
                u16 hi, lo; bsplit(h_, hi, lo);
                const size_t o = ((size_t)t * B_ + brow) * HID_ + j0 + jj;
                Ahi[o] = hi;
                Alo[o] = lo;
            }

            __syncthreads();                       // SYNC_C: stores drained
            if (tid == 0) {
                unsigned old = AADD(shard1);
                if (old + 1u == 16u * (unsigned)(t + 1)) AADD(root1);
            }
        }
    }
}

// ---------------------------------------------------------------------------
extern "C" void kernel_launch(void* const* d_in, const int* in_sizes, int n_in,
                              void* d_out, int out_size, void* d_ws, size_t ws_size,
                              hipStream_t stream)
{
    const int*   tokens = (const int*)  d_in[0];
    const float* emb    = (const float*)d_in[1];
    const float* W0     = (const float*)d_in[2];
    const float* U0     = (const float*)d_in[3];
    const float* b0     = (const float*)d_in[4];
    const float* W1     = (const float*)d_in[5];
    const float* U1     = (const float*)d_in[6];
    const float* b1     = (const float*)d_in[7];
    const float* Wout   = (const float*)d_in[8];
    const float* bout   = (const float*)d_in[9];
    float* out = (float*)d_out;

    // d_out scratch: G (8192x2048 fp32 swizzled, 16.78M floats) then H0x
    // (257*32*512 = 4.21M floats) -- both dead before the final GEMM
    // overwrites all of d_out. ws holds bf16 operands + h1buf + barriers.
    float* G   = out;
    float* H0x = out + (size_t)8192 * 2048;

    u16* ws16 = (u16*)d_ws;
    size_t o = 0;
    u16* Ahi   = ws16 + o; o += (size_t)8192 * 512;
    u16* Alo   = ws16 + o; o += (size_t)8192 * 512;
    u16* W0Thi = ws16 + o; o += (size_t)G4_ * 512;
    u16* W0Tlo = ws16 + o; o += (size_t)G4_ * 512;
    u16* WoThi = ws16 + o; o += (size_t)NPAD_ * 512;
    u16* WoTlo = ws16 + o; o += (size_t)NPAD_ * 512;
    float*    h1buf = (float*)(ws16 + o);
    unsigned* bar   = (unsigned*)(h1buf + 2 * B_ * HID_);

    dim3 blk(256);

    // prep: weight transpose+split (W0, Wout) and embedding gather+split
    wsplit_k<<<dim3(G4_ / 64, 8), blk, 0, stream>>>(W0, W0Thi, W0Tlo, G4_);
    wsplit_k<<<dim3(NPAD_ / 64, 8), blk, 0, stream>>>(Wout, WoThi, WoTlo, VOC_);
    gather_split_k<<<dim3(2048), blk, 0, stream>>>(tokens, emb, Ahi, Alo);

    // G = X0 @ W0 + b0   (split-bf16 MFMA, recurrence-swizzled store)
    gemm_bf16_k<0><<<dim3(G4_ / 128, 64), blk, 0, stream>>>(
        Ahi, Alo, W0Thi, W0Tlo, b0, G, G4_);

    // fused 2-layer recurrence -> Ahi/Alo (h1 bf16)
    hipMemsetAsync(H0x, 0, B_ * HID_ * sizeof(float), stream);    // h0(0) = 0
    hipMemsetAsync(h1buf, 0, B_ * HID_ * sizeof(float), stream);  // h1(0) = 0
    hipMemsetAsync(bar, 0, 1024 * sizeof(unsigned), stream);      // barriers
    fused_rec_k<<<dim3(512), blk, 0, stream>>>(
        G, U0, W1, U1, b1, H0x, Ahi, Alo, h1buf, bar);

    // out[b*T+t, :] = H1 @ W_out + b_out
    gemm_bf16_k<1><<<dim3(NPAD_ / 128, 64), blk, 0, stream>>>(
        Ahi, Alo, WoThi, WoTlo, bout, out, NPAD_);
}